// Round 1
// baseline (240.840 us; speedup 1.0000x reference)
//
#include <hip/hip_runtime.h>
#include <stdint.h>

#define HIDDEN 1024
#define SEQ 4096
#define BATCH 4
#define HEADS 16
#define HDIM 64
#define M_TOT (BATCH * SEQ)   // 16384
#define NCH 16                // split-S chunks for kv reduction

typedef __bf16 bf16x8 __attribute__((ext_vector_type(8)));
typedef float f32x4 __attribute__((ext_vector_type(4)));
typedef unsigned short u16x8 __attribute__((ext_vector_type(8)));

static __device__ __forceinline__ unsigned short f2bf(float f) {
  union { float f; uint32_t u; } v; v.f = f;
  uint32_t u = v.u;
  uint32_t r = (u + 0x7fffu + ((u >> 16) & 1u)) >> 16;
  return (unsigned short)r;
}
static __device__ __forceinline__ float bf2f(unsigned short h) {
  union { uint32_t u; float f; } v; v.u = ((uint32_t)h) << 16;
  return v.f;
}
static __device__ __forceinline__ void load_lds16(const void* g, void* l) {
  __builtin_amdgcn_global_load_lds(
      (__attribute__((address_space(1))) void*)(g),
      (__attribute__((address_space(3))) void*)(l), 16, 0, 0);
}

// ---------------- small prep kernels ----------------

// norm[b] = 1/sqrt(sum(mask[b,:]) * HDIM)
__global__ void masksum_k(const float* __restrict__ mask, float* __restrict__ norm) {
  int b = blockIdx.x;
  int tid = threadIdx.x;
  float s = 0.f;
  for (int i = tid; i < SEQ; i += 256) s += mask[b * SEQ + i];
  for (int off = 32; off; off >>= 1) s += __shfl_down(s, off);
  __shared__ float wsum[4];
  if ((tid & 63) == 0) wsum[tid >> 6] = s;
  __syncthreads();
  if (tid == 0) {
    float t = wsum[0] + wsum[1] + wsum[2] + wsum[3];
    norm[b] = rsqrtf(t * (float)HDIM);
  }
}

// x f32 -> bf16, 8 elems/thread. grid 8192 x 256 covers 16777216 exactly.
__global__ void convert_x_k(const float* __restrict__ x, unsigned short* __restrict__ xb) {
  int idx = blockIdx.x * 256 + threadIdx.x;
  const float4* xv = (const float4*)x;
  float4 a = xv[(size_t)idx * 2];
  float4 b = xv[(size_t)idx * 2 + 1];
  u16x8 o;
  o[0] = f2bf(a.x); o[1] = f2bf(a.y); o[2] = f2bf(a.z); o[3] = f2bf(a.w);
  o[4] = f2bf(b.x); o[5] = f2bf(b.y); o[6] = f2bf(b.z); o[7] = f2bf(b.w);
  *(u16x8*)(xb + (size_t)idx * 8) = o;
}

// Wk,Wv [K][N] f32 -> Bt [2048][1024] bf16 where Bt[n][k] = W[k][n]
__global__ void transw_k(const float* __restrict__ Wk, const float* __restrict__ Wv,
                         unsigned short* __restrict__ Bt) {
  const float* W = blockIdx.z ? Wv : Wk;
  unsigned short* out = Bt + (size_t)blockIdx.z * HIDDEN * HIDDEN;
  __shared__ float ts[64][65];
  int n0 = blockIdx.x * 64, k0 = blockIdx.y * 64;
  int tid = threadIdx.x;
  int c = tid & 63, rq = tid >> 6;
  for (int i = 0; i < 16; ++i) {
    int r = i * 4 + rq;
    ts[r][c] = W[(size_t)(k0 + r) * HIDDEN + n0 + c];
  }
  __syncthreads();
  for (int i = 0; i < 16; ++i) {
    int n = i * 4 + rq;
    out[(size_t)(n0 + n) * HIDDEN + k0 + c] = f2bf(ts[c][n]);
  }
}

// bkv = concat(bk, bv). grid 8 x 256.
__global__ void biascat_k(const float* __restrict__ bk, const float* __restrict__ bv,
                          float* __restrict__ bkv) {
  int i = blockIdx.x * 256 + threadIdx.x;
  bkv[i] = (i < HIDDEN) ? bk[i] : bv[i - HIDDEN];
}

// ---------------- main GEMM (m97-style 128x128, BK=64) ----------------
// C[row][n] = sum_k A[row][k]*Bt[n][k] + bias[n], then * mask[row].
// BF16_OUT: C is bf16 (for K|V). PER_BATCH_B: Bt/bias indexed by batch of row tile.
template <int BF16_OUT, int PER_BATCH_B>
__global__ __launch_bounds__(256, 2) void gemm_bt_k(
    const unsigned short* __restrict__ A, const unsigned short* __restrict__ Bt,
    const float* __restrict__ bias, const float* __restrict__ mask,
    void* __restrict__ C, int ldc) {
  __shared__ unsigned short smem[128 * 128];  // 32 KiB
  unsigned short* As = smem;             // [128][64]
  unsigned short* Bs = smem + 128 * 64;  // [128][64]

  const int tid = threadIdx.x;
  const int row0 = blockIdx.y * 128;
  const int col0 = blockIdx.x * 128;

  const unsigned short* Bbase = Bt;
  const float* biasbase = bias;
  if (PER_BATCH_B) {
    int b = row0 >> 12;  // 4096 rows per batch
    Bbase = Bt + (size_t)b * HIDDEN * HIDDEN;
    biasbase = bias + b * HIDDEN;
  }

  const int sr = tid >> 3;         // 0..31
  const int sk = (tid & 7) * 8;    // 0..56
  const unsigned short* Ag = A + (size_t)(row0 + sr) * HIDDEN + sk;
  const unsigned short* Bg = Bbase + (size_t)(col0 + sr) * HIDDEN + sk;
  unsigned short* Asd = As + sr * 64 + sk;
  unsigned short* Bsd = Bs + sr * 64 + sk;

  const int wave = tid >> 6;
  const int lane = tid & 63;
  const int wr = (wave >> 1) * 64;
  const int wc = (wave & 1) * 64;
  const int lr = lane & 15;
  const int lk8 = (lane >> 4) * 8;

  f32x4 acc[4][4];
#pragma unroll
  for (int i = 0; i < 4; ++i)
#pragma unroll
    for (int j = 0; j < 4; ++j) acc[i][j] = (f32x4){0.f, 0.f, 0.f, 0.f};

  for (int kt = 0; kt < HIDDEN; kt += 64) {
#pragma unroll
    for (int i = 0; i < 4; ++i) {
      load_lds16(Ag + (size_t)i * 32 * HIDDEN + kt, Asd + i * 32 * 64);
      load_lds16(Bg + (size_t)i * 32 * HIDDEN + kt, Bsd + i * 32 * 64);
    }
    __syncthreads();
#pragma unroll
    for (int kk = 0; kk < 2; ++kk) {
      const int ko = kk * 32 + lk8;
      bf16x8 af[4], bfr[4];
#pragma unroll
      for (int mt = 0; mt < 4; ++mt)
        af[mt] = *(const bf16x8*)&As[(wr + mt * 16 + lr) * 64 + ko];
#pragma unroll
      for (int nt = 0; nt < 4; ++nt)
        bfr[nt] = *(const bf16x8*)&Bs[(wc + nt * 16 + lr) * 64 + ko];
#pragma unroll
      for (int mt = 0; mt < 4; ++mt)
#pragma unroll
        for (int nt = 0; nt < 4; ++nt)
          acc[mt][nt] = __builtin_amdgcn_mfma_f32_16x16x32_bf16(af[mt], bfr[nt], acc[mt][nt], 0, 0, 0);
    }
    __syncthreads();
  }

  float bcol[4];
#pragma unroll
  for (int nt = 0; nt < 4; ++nt) bcol[nt] = biasbase[col0 + wc + nt * 16 + lr];

  if (BF16_OUT) {
    __syncthreads();
    unsigned short* Cs = smem;  // [128][128]
#pragma unroll
    for (int mt = 0; mt < 4; ++mt)
#pragma unroll
      for (int j = 0; j < 4; ++j) {
        int r = wr + mt * 16 + (lane >> 4) * 4 + j;
        float mrow = mask[row0 + r];
#pragma unroll
        for (int nt = 0; nt < 4; ++nt) {
          int c = wc + nt * 16 + lr;
          float v = (acc[mt][nt][j] + bcol[nt]) * mrow;
          Cs[r * 128 + c] = f2bf(v);
        }
      }
    __syncthreads();
    unsigned short* Cg = (unsigned short*)C;
#pragma unroll
    for (int i = 0; i < 8; ++i) {
      int off = i * 2048 + tid * 8;
      int r = off >> 7, c = off & 127;
      *(uint4*)(Cg + (size_t)(row0 + r) * ldc + col0 + c) = *(const uint4*)&Cs[off];
    }
  } else {
    float* Cg = (float*)C;
#pragma unroll
    for (int mt = 0; mt < 4; ++mt)
#pragma unroll
      for (int j = 0; j < 4; ++j) {
        int r = wr + mt * 16 + (lane >> 4) * 4 + j;
        float mrow = mask[row0 + r];
#pragma unroll
        for (int nt = 0; nt < 4; ++nt) {
          int c = wc + nt * 16 + lr;
          Cg[(size_t)(row0 + r) * ldc + col0 + c] = (acc[mt][nt][j] + bcol[nt]) * mrow;
        }
      }
  }
}

// ---------------- kv = K^T V (split-S partials, deterministic) ----------------
// KV: [16384][2048] bf16 (K cols 0..1023, V cols 1024..2047)
// part: [NCH][64][64][64] f32
__global__ __launch_bounds__(256) void kvpart_k(const unsigned short* __restrict__ KV,
                                                float* __restrict__ part) {
  int bh = blockIdx.x;  // b*16+h
  int ch = blockIdx.y;
  int b = bh >> 4, h = bh & 15;
  int s0 = ch * (SEQ / NCH);
  const unsigned short* Kp = KV + ((size_t)(b * SEQ + s0)) * 2048 + h * 64;
  const unsigned short* Vp = Kp + 1024;
  __shared__ float ks[4][64], vs[4][64];
  int tid = threadIdx.x;
  int r = tid >> 6, c = tid & 63;
  int ti = tid >> 4, tj = tid & 15;
  float acc[4][4] = {};
  for (int s4 = 0; s4 < SEQ / NCH; s4 += 4) {
    __syncthreads();
    ks[r][c] = bf2f(Kp[(size_t)(s4 + r) * 2048 + c]);
    vs[r][c] = bf2f(Vp[(size_t)(s4 + r) * 2048 + c]);
    __syncthreads();
#pragma unroll
    for (int ss = 0; ss < 4; ++ss) {
      f32x4 kd = *(const f32x4*)&ks[ss][ti * 4];
      f32x4 ve = *(const f32x4*)&vs[ss][tj * 4];
#pragma unroll
      for (int a = 0; a < 4; ++a)
#pragma unroll
        for (int e = 0; e < 4; ++e) acc[a][e] += kd[a] * ve[e];
    }
  }
  float* dst = part + ((size_t)(ch * 64 + bh)) * 4096 + (ti * 4) * 64 + tj * 4;
#pragma unroll
  for (int a = 0; a < 4; ++a) {
    f32x4 v = {acc[a][0], acc[a][1], acc[a][2], acc[a][3]};
    *(f32x4*)&dst[a * 64] = v;
  }
}

// kv[bh*4096 + d*64 + e] = norm[b] * sum_ch part  (grid 1024 x 256)
__global__ void kvreduce_k(const float* __restrict__ part, const float* __restrict__ norm,
                           float* __restrict__ kv) {
  int idx = blockIdx.x * 256 + threadIdx.x;  // 0..262143
  int b = idx >> 16;                         // bh = idx>>12, b = bh>>4
  float s = 0.f;
#pragma unroll
  for (int ch = 0; ch < NCH; ++ch) s += part[(size_t)ch * 262144 + idx];
  kv[idx] = s * norm[b];
}

// bias2[b][n] = sum_d bq[h*64+d] * kv[b,h,d,e]   (grid 16 x 256)
__global__ void bias2_k(const float* __restrict__ bq, const float* __restrict__ kv,
                        float* __restrict__ bias2) {
  int idx = blockIdx.x * 256 + threadIdx.x;  // 0..4095
  int b = idx >> 10, n = idx & 1023, h = n >> 6, e = n & 63;
  const float* kvp = kv + ((size_t)(b * 16 + h)) * 4096 + e;
  float s = 0.f;
#pragma unroll
  for (int d = 0; d < 64; ++d) s += bq[h * 64 + d] * kvp[d * 64];
  bias2[idx] = s;
}

// W't[b][h*64+e][c] = sum_d Wq[c][h*64+d] * kv[b,h,d,e]  -> bf16
// grid (cblk=8, bh=64), block 128 threads (one c per thread)
__global__ __launch_bounds__(128) void wprime_k(const float* __restrict__ Wq,
                                                const float* __restrict__ kv,
                                                unsigned short* __restrict__ Wpt) {
  int bh = blockIdx.y, b = bh >> 4, h = bh & 15;
  int c0 = blockIdx.x * 128;
  __shared__ float wqs[128][65];
  __shared__ float kvs[64][64];
  int tid = threadIdx.x;
  for (int i = 0; i < 32; ++i) {
    int idx = i * 128 + tid;
    ((float*)kvs)[idx] = kv[(size_t)bh * 4096 + idx];
  }
  int rr = tid >> 6, cc = tid & 63;
  for (int i = 0; i < 64; ++i) {
    int r = i * 2 + rr;
    wqs[r][cc] = Wq[(size_t)(c0 + r) * HIDDEN + h * 64 + cc];
  }
  __syncthreads();
  float acc[64];
#pragma unroll
  for (int e = 0; e < 64; ++e) acc[e] = 0.f;
  for (int d = 0; d < 64; ++d) {
    float w = wqs[tid][d];
#pragma unroll
    for (int e4 = 0; e4 < 64; e4 += 4) {
      f32x4 kvv = *(const f32x4*)&kvs[d][e4];
      acc[e4 + 0] += w * kvv[0];
      acc[e4 + 1] += w * kvv[1];
      acc[e4 + 2] += w * kvv[2];
      acc[e4 + 3] += w * kvv[3];
    }
  }
  unsigned short* dst = Wpt + (size_t)b * HIDDEN * HIDDEN + (size_t)(h * 64) * HIDDEN + (c0 + tid);
#pragma unroll
  for (int e = 0; e < 64; ++e) dst[(size_t)e * HIDDEN] = f2bf(acc[e]);
}

// ---------------- launch ----------------
extern "C" void kernel_launch(void* const* d_in, const int* in_sizes, int n_in,
                              void* d_out, int out_size, void* d_ws, size_t ws_size,
                              hipStream_t stream) {
  const float* x = (const float*)d_in[0];
  const float* mask = (const float*)d_in[1];
  const float* Wq = (const float*)d_in[2];
  const float* bq = (const float*)d_in[3];
  const float* Wk = (const float*)d_in[4];
  const float* bk = (const float*)d_in[5];
  const float* Wv = (const float*)d_in[6];
  const float* bv = (const float*)d_in[7];
  float* out = (float*)d_out;

  char* w = (char*)d_ws;
  unsigned short* xb = (unsigned short*)w; w += (size_t)M_TOT * HIDDEN * 2;          // 32 MiB
  unsigned short* Bt = (unsigned short*)w; w += (size_t)2048 * HIDDEN * 2;           // 4 MiB
  unsigned short* KV = (unsigned short*)w; w += (size_t)M_TOT * 2048 * 2;            // 64 MiB
  float* part = (float*)w;                 w += (size_t)NCH * 64 * 4096 * 4;         // 16 MiB
  float* kv = (float*)w;                   w += (size_t)64 * 4096 * 4;               // 1 MiB
  unsigned short* Wpt = (unsigned short*)w; w += (size_t)BATCH * HIDDEN * HIDDEN * 2; // 8 MiB
  float* bkv = (float*)w;                  w += 2048 * 4;
  float* bias2 = (float*)w;                w += 4096 * 4;
  float* norm = (float*)w;                 w += 64;

  masksum_k<<<dim3(BATCH), dim3(256), 0, stream>>>(mask, norm);
  convert_x_k<<<dim3(8192), dim3(256), 0, stream>>>(x, xb);
  transw_k<<<dim3(16, 16, 2), dim3(256), 0, stream>>>(Wk, Wv, Bt);
  biascat_k<<<dim3(8), dim3(256), 0, stream>>>(bk, bv, bkv);
  gemm_bt_k<1, 0><<<dim3(16, 128), dim3(256), 0, stream>>>(xb, Bt, bkv, mask, (void*)KV, 2048);
  kvpart_k<<<dim3(64, NCH), dim3(256), 0, stream>>>(KV, part);
  kvreduce_k<<<dim3(1024), dim3(256), 0, stream>>>(part, norm, kv);
  bias2_k<<<dim3(16), dim3(256), 0, stream>>>(bq, kv, bias2);
  wprime_k<<<dim3(8, 64), dim3(128), 0, stream>>>(Wq, kv, Wpt);
  gemm_bt_k<0, 1><<<dim3(8, 128), dim3(256), 0, stream>>>(xb, Wpt, bias2, mask, (void*)out, HIDDEN);
}

// Round 2
// 206.734 us; speedup vs baseline: 1.1650x; 1.1650x over previous
//
#include <hip/hip_runtime.h>
#include <stdint.h>

#define HIDDEN 1024
#define SEQ 4096
#define BATCH 4
#define HEADS 16
#define HDIM 64
#define M_TOT (BATCH * SEQ)   // 16384
#define NCH 16                // split-S chunks for kv reduction
#define NT 32                 // K-tiles of 32 in the 256^2 GEMM

typedef __bf16 bf16x8 __attribute__((ext_vector_type(8)));
typedef float f32x4 __attribute__((ext_vector_type(4)));
typedef unsigned short u16x8 __attribute__((ext_vector_type(8)));

static __device__ __forceinline__ unsigned short f2bf(float f) {
  union { float f; uint32_t u; } v; v.f = f;
  uint32_t u = v.u;
  uint32_t r = (u + 0x7fffu + ((u >> 16) & 1u)) >> 16;
  return (unsigned short)r;
}
static __device__ __forceinline__ float bf2f(unsigned short h) {
  union { uint32_t u; float f; } v; v.u = ((uint32_t)h) << 16;
  return v.f;
}
static __device__ __forceinline__ void load_lds16(const void* g, void* l) {
  __builtin_amdgcn_global_load_lds(
      (__attribute__((address_space(1))) void*)(g),
      (__attribute__((address_space(3))) void*)(l), 16, 0, 0);
}

// ---------------- small prep kernels ----------------

__global__ void masksum_k(const float* __restrict__ mask, float* __restrict__ norm) {
  int b = blockIdx.x;
  int tid = threadIdx.x;
  float s = 0.f;
  for (int i = tid; i < SEQ; i += 256) s += mask[b * SEQ + i];
  for (int off = 32; off; off >>= 1) s += __shfl_down(s, off);
  __shared__ float wsum[4];
  if ((tid & 63) == 0) wsum[tid >> 6] = s;
  __syncthreads();
  if (tid == 0) {
    float t = wsum[0] + wsum[1] + wsum[2] + wsum[3];
    norm[b] = rsqrtf(t * (float)HDIM);
  }
}

__global__ void convert_x_k(const float* __restrict__ x, unsigned short* __restrict__ xb) {
  int idx = blockIdx.x * 256 + threadIdx.x;
  const float4* xv = (const float4*)x;
  float4 a = xv[(size_t)idx * 2];
  float4 b = xv[(size_t)idx * 2 + 1];
  u16x8 o;
  o[0] = f2bf(a.x); o[1] = f2bf(a.y); o[2] = f2bf(a.z); o[3] = f2bf(a.w);
  o[4] = f2bf(b.x); o[5] = f2bf(b.y); o[6] = f2bf(b.z); o[7] = f2bf(b.w);
  *(u16x8*)(xb + (size_t)idx * 8) = o;
}

__global__ void transw_k(const float* __restrict__ Wk, const float* __restrict__ Wv,
                         unsigned short* __restrict__ Bt) {
  const float* W = blockIdx.z ? Wv : Wk;
  unsigned short* out = Bt + (size_t)blockIdx.z * HIDDEN * HIDDEN;
  __shared__ float ts[64][65];
  int n0 = blockIdx.x * 64, k0 = blockIdx.y * 64;
  int tid = threadIdx.x;
  int c = tid & 63, rq = tid >> 6;
  for (int i = 0; i < 16; ++i) {
    int r = i * 4 + rq;
    ts[r][c] = W[(size_t)(k0 + r) * HIDDEN + n0 + c];
  }
  __syncthreads();
  for (int i = 0; i < 16; ++i) {
    int n = i * 4 + rq;
    out[(size_t)(n0 + n) * HIDDEN + k0 + c] = f2bf(ts[c][n]);
  }
}

__global__ void biascat_k(const float* __restrict__ bk, const float* __restrict__ bv,
                          float* __restrict__ bkv) {
  int i = blockIdx.x * 256 + threadIdx.x;
  bkv[i] = (i < HIDDEN) ? bk[i] : bv[i - HIDDEN];
}

// ---------------- 256x256 pipelined GEMM (BK=32, 4-buffer ring, counted vmcnt) --------
// C[row][n] = sum_k A[row][k]*Bt[n][k] + bias[n], then * mask[row].
#define MFMA4(am, AF) \
  acc[am][0] = __builtin_amdgcn_mfma_f32_16x16x32_bf16(AF, b0, acc[am][0], 0, 0, 0); \
  acc[am][1] = __builtin_amdgcn_mfma_f32_16x16x32_bf16(AF, b1, acc[am][1], 0, 0, 0); \
  acc[am][2] = __builtin_amdgcn_mfma_f32_16x16x32_bf16(AF, b2, acc[am][2], 0, 0, 0); \
  acc[am][3] = __builtin_amdgcn_mfma_f32_16x16x32_bf16(AF, b3, acc[am][3], 0, 0, 0);

template <int BF16_OUT, int PER_BATCH_B>
__global__ __launch_bounds__(512, 1) void gemm256_k(
    const unsigned short* __restrict__ A, const unsigned short* __restrict__ Bt,
    const float* __restrict__ bias, const float* __restrict__ mask,
    void* __restrict__ C, int ldc, int nbn) {
  __shared__ unsigned short smem[65536];  // 128 KiB: 4 bufs x (A 8192 + B 8192) elems

  // XCD-aware bijective swizzle (gridDim.x % 8 == 0 for both uses)
  const int nwg = gridDim.x;
  const int bid = blockIdx.x;
  const int wg = (bid & 7) * (nwg >> 3) + (bid >> 3);
  const int row0 = (wg / nbn) * 256;
  const int col0 = (wg % nbn) * 256;

  const unsigned short* Bbase = Bt;
  const float* biasbase = bias;
  if (PER_BATCH_B) {
    int b = row0 >> 12;
    Bbase = Bt + (size_t)b * HIDDEN * HIDDEN;
    biasbase = bias + b * HIDDEN;
  }

  const int tid = threadIdx.x;
  const int wave = tid >> 6;
  const int lane = tid & 63;
  const int wm = wave >> 2;       // 0..1  (M half: 128 rows)
  const int wn = wave & 3;        // 0..3  (N quarter: 64 cols)
  const int lr = lane & 15;
  const int hi = lane >> 4;       // 0..3 (k-chunk for frags / row-group for C)

  // --- staging source pointers (inverse-swizzled global, linear LDS dest) ---
  // linear LDS elem (i*512+tid)*8 -> row r=(i*512+tid)>>2, chunk c=tid&3 of [256][4x8elem]
  const int c4 = tid & 3;
  const int rs0 = tid >> 2;          // i=0 rows 0..127
  const int rs1 = 128 + (tid >> 2);  // i=1 rows 128..255
  const int sc0 = ((c4 ^ ((rs0 >> 1) & 3)) << 3);
  const int sc1 = ((c4 ^ ((rs1 >> 1) & 3)) << 3);
  const unsigned short* sA0 = A + (size_t)(row0 + rs0) * HIDDEN + sc0;
  const unsigned short* sA1 = A + (size_t)(row0 + rs1) * HIDDEN + sc1;
  const unsigned short* sB0 = Bbase + (size_t)(col0 + rs0) * HIDDEN + sc0;
  const unsigned short* sB1 = Bbase + (size_t)(col0 + rs1) * HIDDEN + sc1;

  // --- swizzled LDS read offsets for MFMA fragments ---
  int aoff[2][4], boff[4];
#pragma unroll
  for (int ph = 0; ph < 2; ++ph)
#pragma unroll
    for (int mt = 0; mt < 4; ++mt) {
      int ra = wm * 128 + ph * 64 + mt * 16 + lr;
      aoff[ph][mt] = ra * 32 + ((hi ^ ((ra >> 1) & 3)) << 3);
    }
#pragma unroll
  for (int nt = 0; nt < 4; ++nt) {
    int rb = wn * 64 + nt * 16 + lr;
    boff[nt] = 8192 + rb * 32 + ((hi ^ ((rb >> 1) & 3)) << 3);
  }

  f32x4 acc[8][4];
#pragma unroll
  for (int i = 0; i < 8; ++i)
#pragma unroll
    for (int j = 0; j < 4; ++j) acc[i][j] = (f32x4){0.f, 0.f, 0.f, 0.f};

#define STAGE_A(t2) { int bb2 = ((t2) & 3) * 16384; \
    load_lds16(sA0 + (t2) * 32, &smem[bb2 + tid * 8]); \
    load_lds16(sA1 + (t2) * 32, &smem[bb2 + 4096 + tid * 8]); }
#define STAGE_B(t2) { int bb2 = ((t2) & 3) * 16384; \
    load_lds16(sB0 + (t2) * 32, &smem[bb2 + 8192 + tid * 8]); \
    load_lds16(sB1 + (t2) * 32, &smem[bb2 + 12288 + tid * 8]); }

  // prologue: tiles 0 and 1 in flight; wait tile 0 (4 newest = tile 1)
  STAGE_A(0); STAGE_B(0); STAGE_A(1); STAGE_B(1);
  asm volatile("s_waitcnt vmcnt(4)" ::: "memory");
  __builtin_amdgcn_s_barrier();

  for (int t = 0; t < NT; ++t) {
    const int bb = (t & 3) * 16384;
    bf16x8 af0, af1, af2, af3, b0, b1, b2, b3;
    // ---- phase 0: quadrant mh=0, all n ----
    af0 = *(const bf16x8*)&smem[bb + aoff[0][0]];
    af1 = *(const bf16x8*)&smem[bb + aoff[0][1]];
    af2 = *(const bf16x8*)&smem[bb + aoff[0][2]];
    af3 = *(const bf16x8*)&smem[bb + aoff[0][3]];
    b0 = *(const bf16x8*)&smem[bb + boff[0]];
    b1 = *(const bf16x8*)&smem[bb + boff[1]];
    b2 = *(const bf16x8*)&smem[bb + boff[2]];
    b3 = *(const bf16x8*)&smem[bb + boff[3]];
    if (t + 2 < NT) STAGE_A(t + 2);
    asm volatile("" ::: "memory");
    __builtin_amdgcn_s_barrier();
    __builtin_amdgcn_s_setprio(1);
    MFMA4(0, af0) MFMA4(1, af1) MFMA4(2, af2) MFMA4(3, af3)
    __builtin_amdgcn_s_setprio(0);
    asm volatile("" ::: "memory");
    __builtin_amdgcn_s_barrier();
    // ---- phase 1: quadrant mh=1, all n (reuse B frags) ----
    af0 = *(const bf16x8*)&smem[bb + aoff[1][0]];
    af1 = *(const bf16x8*)&smem[bb + aoff[1][1]];
    af2 = *(const bf16x8*)&smem[bb + aoff[1][2]];
    af3 = *(const bf16x8*)&smem[bb + aoff[1][3]];
    if (t + 2 < NT) STAGE_B(t + 2);
    asm volatile("" ::: "memory");
    __builtin_amdgcn_s_barrier();
    __builtin_amdgcn_s_setprio(1);
    MFMA4(4, af0) MFMA4(5, af1) MFMA4(6, af2) MFMA4(7, af3)
    __builtin_amdgcn_s_setprio(0);
    // boundary: tile t+1 must be fully arrived; newest 4 loads are tile t+2's
    if (t < NT - 2) asm volatile("s_waitcnt vmcnt(4)" ::: "memory");
    else            asm volatile("s_waitcnt vmcnt(0)" ::: "memory");
    __builtin_amdgcn_s_barrier();
  }

  // ---- epilogue ----
  float bcol[4];
#pragma unroll
  for (int nt = 0; nt < 4; ++nt) bcol[nt] = biasbase[col0 + wn * 64 + nt * 16 + lr];

  if (BF16_OUT) {
    asm volatile("" ::: "memory");
    __builtin_amdgcn_s_barrier();
    unsigned short* wa = &smem[wave * 8192];  // per-wave [128][64]
#pragma unroll
    for (int am = 0; am < 8; ++am) {
      int rbase = (am >> 2) * 64 + (am & 3) * 16 + hi * 4;
#pragma unroll
      for (int j = 0; j < 4; ++j) {
        int r = rbase + j;
        float mrow = mask[row0 + wm * 128 + r];
#pragma unroll
        for (int nt = 0; nt < 4; ++nt)
          wa[r * 64 + nt * 16 + lr] = f2bf((acc[am][nt][j] + bcol[nt]) * mrow);
      }
    }
    unsigned short* Cg = (unsigned short*)C;
    size_t cbase = (size_t)(row0 + wm * 128) * ldc + col0 + wn * 64;
#pragma unroll
    for (int i = 0; i < 16; ++i) {
      int elem = i * 512 + lane * 8;
      int r = elem >> 6, cc = elem & 63;
      *(uint4*)&Cg[cbase + (size_t)r * ldc + cc] = *(const uint4*)&wa[elem];
    }
  } else {
    float* Cg = (float*)C;
#pragma unroll
    for (int am = 0; am < 8; ++am) {
#pragma unroll
      for (int j = 0; j < 4; ++j) {
        int r = row0 + wm * 128 + (am >> 2) * 64 + (am & 3) * 16 + hi * 4 + j;
        float mrow = mask[r];
#pragma unroll
        for (int nt = 0; nt < 4; ++nt) {
          int cc = col0 + wn * 64 + nt * 16 + lr;
          Cg[(size_t)r * ldc + cc] = (acc[am][nt][j] + bcol[nt]) * mrow;
        }
      }
    }
  }
}

// ---------------- kv = K^T V (split-S partials, deterministic) ----------------
__global__ __launch_bounds__(256) void kvpart_k(const unsigned short* __restrict__ KV,
                                                float* __restrict__ part) {
  int bh = blockIdx.x;  // b*16+h
  int ch = blockIdx.y;
  int b = bh >> 4, h = bh & 15;
  int s0 = ch * (SEQ / NCH);
  const unsigned short* Kp = KV + ((size_t)(b * SEQ + s0)) * 2048 + h * 64;
  const unsigned short* Vp = Kp + 1024;
  __shared__ float ks[32][64], vs[32][64];
  int tid = threadIdx.x;
  int lrow = tid >> 3, lcol = (tid & 7) * 8;
  int ti = tid >> 4, tj = tid & 15;
  float acc[4][4] = {};
  for (int s32 = 0; s32 < SEQ / NCH; s32 += 32) {
    __syncthreads();
    u16x8 k8 = *(const u16x8*)&Kp[(size_t)(s32 + lrow) * 2048 + lcol];
    u16x8 v8 = *(const u16x8*)&Vp[(size_t)(s32 + lrow) * 2048 + lcol];
#pragma unroll
    for (int e = 0; e < 8; ++e) {
      ks[lrow][lcol + e] = bf2f(k8[e]);
      vs[lrow][lcol + e] = bf2f(v8[e]);
    }
    __syncthreads();
#pragma unroll
    for (int ss = 0; ss < 32; ++ss) {
      f32x4 kd = *(const f32x4*)&ks[ss][ti * 4];
      f32x4 ve = *(const f32x4*)&vs[ss][tj * 4];
#pragma unroll
      for (int a = 0; a < 4; ++a)
#pragma unroll
        for (int e = 0; e < 4; ++e) acc[a][e] += kd[a] * ve[e];
    }
  }
  float* dst = part + ((size_t)(ch * 64 + bh)) * 4096 + (ti * 4) * 64 + tj * 4;
#pragma unroll
  for (int a = 0; a < 4; ++a) {
    f32x4 v = {acc[a][0], acc[a][1], acc[a][2], acc[a][3]};
    *(f32x4*)&dst[a * 64] = v;
  }
}

__global__ void kvreduce_k(const float* __restrict__ part, const float* __restrict__ norm,
                           float* __restrict__ kv) {
  int idx = blockIdx.x * 256 + threadIdx.x;
  int b = idx >> 16;
  float s = 0.f;
#pragma unroll
  for (int ch = 0; ch < NCH; ++ch) s += part[(size_t)ch * 262144 + idx];
  kv[idx] = s * norm[b];
}

__global__ void bias2_k(const float* __restrict__ bq, const float* __restrict__ kv,
                        float* __restrict__ bias2) {
  int idx = blockIdx.x * 256 + threadIdx.x;
  int b = idx >> 10, n = idx & 1023, h = n >> 6, e = n & 63;
  const float* kvp = kv + ((size_t)(b * 16 + h)) * 4096 + e;
  float s = 0.f;
#pragma unroll
  for (int d = 0; d < 64; ++d) s += bq[h * 64 + d] * kvp[d * 64];
  bias2[idx] = s;
}

__global__ __launch_bounds__(128) void wprime_k(const float* __restrict__ Wq,
                                                const float* __restrict__ kv,
                                                unsigned short* __restrict__ Wpt) {
  int bh = blockIdx.y, b = bh >> 4, h = bh & 15;
  int c0 = blockIdx.x * 128;
  __shared__ float wqs[128][65];
  __shared__ float kvs[64][64];
  int tid = threadIdx.x;
  for (int i = 0; i < 32; ++i) {
    int idx = i * 128 + tid;
    ((float*)kvs)[idx] = kv[(size_t)bh * 4096 + idx];
  }
  int rr = tid >> 6, cc = tid & 63;
  for (int i = 0; i < 64; ++i) {
    int r = i * 2 + rr;
    wqs[r][cc] = Wq[(size_t)(c0 + r) * HIDDEN + h * 64 + cc];
  }
  __syncthreads();
  float acc[64];
#pragma unroll
  for (int e = 0; e < 64; ++e) acc[e] = 0.f;
  for (int d = 0; d < 64; ++d) {
    float w = wqs[tid][d];
#pragma unroll
    for (int e4 = 0; e4 < 64; e4 += 4) {
      f32x4 kvv = *(const f32x4*)&kvs[d][e4];
      acc[e4 + 0] += w * kvv[0];
      acc[e4 + 1] += w * kvv[1];
      acc[e4 + 2] += w * kvv[2];
      acc[e4 + 3] += w * kvv[3];
    }
  }
  unsigned short* dst = Wpt + (size_t)b * HIDDEN * HIDDEN + (size_t)(h * 64) * HIDDEN + (c0 + tid);
#pragma unroll
  for (int e = 0; e < 64; ++e) dst[(size_t)e * HIDDEN] = f2bf(acc[e]);
}

// ---------------- launch ----------------
extern "C" void kernel_launch(void* const* d_in, const int* in_sizes, int n_in,
                              void* d_out, int out_size, void* d_ws, size_t ws_size,
                              hipStream_t stream) {
  const float* x = (const float*)d_in[0];
  const float* mask = (const float*)d_in[1];
  const float* Wq = (const float*)d_in[2];
  const float* bq = (const float*)d_in[3];
  const float* Wk = (const float*)d_in[4];
  const float* bk = (const float*)d_in[5];
  const float* Wv = (const float*)d_in[6];
  const float* bv = (const float*)d_in[7];
  float* out = (float*)d_out;

  char* w = (char*)d_ws;
  unsigned short* xb = (unsigned short*)w; w += (size_t)M_TOT * HIDDEN * 2;           // 32 MiB
  unsigned short* Bt = (unsigned short*)w; w += (size_t)2048 * HIDDEN * 2;            // 4 MiB
  unsigned short* KV = (unsigned short*)w; w += (size_t)M_TOT * 2048 * 2;             // 64 MiB
  float* part = (float*)w;                 w += (size_t)NCH * 64 * 4096 * 4;          // 16 MiB
  float* kv = (float*)w;                   w += (size_t)64 * 4096 * 4;                // 1 MiB
  unsigned short* Wpt = (unsigned short*)w; w += (size_t)BATCH * HIDDEN * HIDDEN * 2; // 8 MiB
  float* bkv = (float*)w;                  w += 2048 * 4;
  float* bias2 = (float*)w;                w += 4096 * 4;
  float* norm = (float*)w;                 w += 64;

  masksum_k<<<dim3(BATCH), dim3(256), 0, stream>>>(mask, norm);
  convert_x_k<<<dim3(8192), dim3(256), 0, stream>>>(x, xb);
  transw_k<<<dim3(16, 16, 2), dim3(256), 0, stream>>>(Wk, Wv, Bt);
  biascat_k<<<dim3(8), dim3(256), 0, stream>>>(bk, bv, bkv);
  // KV projection: M=16384, N=2048, K=1024 -> grid 64*8=512 blocks
  gemm256_k<1, 0><<<dim3(512), dim3(512), 0, stream>>>(xb, Bt, bkv, mask, (void*)KV, 2048, 8);
  kvpart_k<<<dim3(64, NCH), dim3(256), 0, stream>>>(KV, part);
  kvreduce_k<<<dim3(1024), dim3(256), 0, stream>>>(part, norm, kv);
  bias2_k<<<dim3(16), dim3(256), 0, stream>>>(bq, kv, bias2);
  wprime_k<<<dim3(8, 64), dim3(128), 0, stream>>>(Wq, kv, Wpt);
  // out GEMM: M=16384, N=1024, K=1024 -> grid 64*4=256 blocks
  gemm256_k<0, 1><<<dim3(256), dim3(512), 0, stream>>>(xb, Wpt, bias2, mask, (void*)out, 1024, 4);
}

// Round 4
// 200.220 us; speedup vs baseline: 1.2029x; 1.0325x over previous
//
#include <hip/hip_runtime.h>
#include <stdint.h>

#define HIDDEN 1024
#define SEQ 4096
#define BATCH 4
#define HEADS 16
#define HDIM 64
#define M_TOT (BATCH * SEQ)   // 16384
#define NCH 16                // split-S chunks for kv reduction
#define NT64 16               // K-steps of 64

typedef __bf16 bf16x8 __attribute__((ext_vector_type(8)));
typedef float f32x4 __attribute__((ext_vector_type(4)));
typedef unsigned short u16x8 __attribute__((ext_vector_type(8)));

static __device__ __forceinline__ unsigned short f2bf(float f) {
  union { float f; uint32_t u; } v; v.f = f;
  uint32_t u = v.u;
  uint32_t r = (u + 0x7fffu + ((u >> 16) & 1u)) >> 16;
  return (unsigned short)r;
}
static __device__ __forceinline__ float bf2f(unsigned short h) {
  union { uint32_t u; float f; } v; v.u = ((uint32_t)h) << 16;
  return v.f;
}
static __device__ __forceinline__ void load_lds16(const void* g, void* l) {
  __builtin_amdgcn_global_load_lds(
      (__attribute__((address_space(1))) void*)(g),
      (__attribute__((address_space(3))) void*)(l), 16, 0, 0);
}

// ---------------- small prep kernels ----------------

__global__ void masksum_k(const float* __restrict__ mask, float* __restrict__ norm) {
  int b = blockIdx.x;
  int tid = threadIdx.x;
  float s = 0.f;
  for (int i = tid; i < SEQ; i += 256) s += mask[b * SEQ + i];
  for (int off = 32; off; off >>= 1) s += __shfl_down(s, off);
  __shared__ float wsum[4];
  if ((tid & 63) == 0) wsum[tid >> 6] = s;
  __syncthreads();
  if (tid == 0) {
    float t = wsum[0] + wsum[1] + wsum[2] + wsum[3];
    norm[b] = rsqrtf(t * (float)HDIM);
  }
}

__global__ void convert_x_k(const float* __restrict__ x, unsigned short* __restrict__ xb) {
  int idx = blockIdx.x * 256 + threadIdx.x;
  const float4* xv = (const float4*)x;
  float4 a = xv[(size_t)idx * 2];
  float4 b = xv[(size_t)idx * 2 + 1];
  u16x8 o;
  o[0] = f2bf(a.x); o[1] = f2bf(a.y); o[2] = f2bf(a.z); o[3] = f2bf(a.w);
  o[4] = f2bf(b.x); o[5] = f2bf(b.y); o[6] = f2bf(b.z); o[7] = f2bf(b.w);
  *(u16x8*)(xb + (size_t)idx * 8) = o;
}

__global__ void transw_k(const float* __restrict__ Wk, const float* __restrict__ Wv,
                         unsigned short* __restrict__ Bt) {
  const float* W = blockIdx.z ? Wv : Wk;
  unsigned short* out = Bt + (size_t)blockIdx.z * HIDDEN * HIDDEN;
  __shared__ float ts[64][65];
  int n0 = blockIdx.x * 64, k0 = blockIdx.y * 64;
  int tid = threadIdx.x;
  int c = tid & 63, rq = tid >> 6;
  for (int i = 0; i < 16; ++i) {
    int r = i * 4 + rq;
    ts[r][c] = W[(size_t)(k0 + r) * HIDDEN + n0 + c];
  }
  __syncthreads();
  for (int i = 0; i < 16; ++i) {
    int n = i * 4 + rq;
    out[(size_t)(n0 + n) * HIDDEN + k0 + c] = f2bf(ts[c][n]);
  }
}

__global__ void biascat_k(const float* __restrict__ bk, const float* __restrict__ bv,
                          float* __restrict__ bkv) {
  int i = blockIdx.x * 256 + threadIdx.x;
  bkv[i] = (i < HIDDEN) ? bk[i] : bv[i - HIDDEN];
}

// ---------------- 256x256 8-phase GEMM (BK=64, dbuf=2, counted vmcnt(6)) ----------
// C[row][n] = sum_k A[row][k]*Bt[n][k] + bias[n], then * mask[row].
// Stage schedule (slot-safety proven):
//   P1: A1(t+1) -> buf (t+1)&1 (holds tile t-1's A-half1, consumed P3 of t-1)
//   P2: (none)  -- nothing in buf t&1 is fully consumed yet
//   P3: B0(t+2) -> buf t&1 B-half0 (consumed by wn=0,1 at P1/P2 of t)
//   P4: A0(t+2) -> buf t&1 A-half0 (consumed by wm=0 at P1/P3 of t)
//       B1(t+2) -> buf t&1 B-half1 (consumed by wn=2,3 at P1/P2 of t)
// End-of-P4 vmcnt(6): 6 newest = {B1,A0,B0}(t+2); forces A1(t+1)+older => tile t+1 landed.
template <int BF16_OUT, int PER_BATCH_B>
__global__ __launch_bounds__(512, 2) void gemm256_k(
    const unsigned short* __restrict__ A, const unsigned short* __restrict__ Bt,
    const float* __restrict__ bias, const float* __restrict__ mask,
    void* __restrict__ C, int ldc, int nbn) {
  __shared__ unsigned short smem[65536];  // 128 KiB: 2 bufs x (A 256x64 + B 256x64)

  const int nwg = gridDim.x;
  const int bid = blockIdx.x;
  const int wg = (bid & 7) * (nwg >> 3) + (bid >> 3);  // XCD swizzle (nwg%8==0)
  const int row0 = (wg / nbn) * 256;
  const int col0 = (wg % nbn) * 256;

  const unsigned short* Bbase = Bt;
  const float* biasbase = bias;
  if (PER_BATCH_B) {
    int b = row0 >> 12;
    Bbase = Bt + (size_t)b * HIDDEN * HIDDEN;
    biasbase = bias + b * HIDDEN;
  }

  const int tid = threadIdx.x;
  const int wave = tid >> 6;
  const int lane = tid & 63;
  const int wm = wave >> 2;   // 0..1 (M half)
  const int wn = wave & 3;    // 0..3 (N quarter)
  const int lr = lane & 15;
  const int hi = lane >> 4;   // 0..3

  // staging: linear LDS dest, inverse-swizzled global source (chunk ^= row&7)
  const int srow = tid >> 3;                        // 0..63
  const int scol = ((tid & 7) ^ (srow & 7)) * 8;    // (row&7)-XORed 16B chunk
  const unsigned short* sA = A + (size_t)(row0 + srow) * HIDDEN + scol;
  const unsigned short* sB = Bbase + (size_t)(col0 + srow) * HIDDEN + scol;
  const int ldst = tid * 8;

  // half-tile stage: 2 x global_load_lds(16B). half: 0=rows[0,128) 1=rows[128,256)
#define STAGE(half, tt, isB) { \
    int dst_ = ((tt)&1) * 32768 + (isB) * 16384 + (half) * 8192 + ldst; \
    const unsigned short* src_ = ((isB) ? sB : sA) + (size_t)(half) * 128 * HIDDEN + (tt) * 64; \
    load_lds16(src_, &smem[dst_]); \
    load_lds16(src_ + (size_t)64 * HIDDEN, &smem[dst_ + 4096]); }

  // swizzled frag read offsets: row ra -> ra*64 + ((k8 ^ (ra&7))*8); ra&7 == lr&7
  const int chunk0 = (hi ^ (lr & 7)) * 8;          // kh=0
  const int chunk1 = ((4 + hi) ^ (lr & 7)) * 8;    // kh=1
  const int arow = (wm * 128 + lr) * 64;           // + rf*1024 (+4096 for m-half 1)
  const int brow = 16384 + (wn * 64 + lr) * 64;    // + cf*1024 (+2048 for n-sub 1)

  f32x4 acc[8][4];
#pragma unroll
  for (int i = 0; i < 8; ++i)
#pragma unroll
    for (int j = 0; j < 4; ++j) acc[i][j] = (f32x4){0.f, 0.f, 0.f, 0.f};

  // prologue: K0 full + A0,B0,B1 of K1 (14 loads); oldest 8 (=K0) must land
  STAGE(0, 0, 0) STAGE(0, 0, 1) STAGE(1, 0, 1) STAGE(1, 0, 0)
  STAGE(0, 1, 0) STAGE(0, 1, 1) STAGE(1, 1, 1)
  asm volatile("s_waitcnt vmcnt(6)" ::: "memory");
  __builtin_amdgcn_s_barrier();

  bf16x8 af[4][2], b0f[2][2], b1f[2][2];
  for (int t = 0; t < NT64; ++t) {
    const int bb = (t & 1) * 32768;
    // ---- P1: read A(rows wm*128+0..63) + B-sub0; stage A1(t+1); MFMA (m0,n0) ----
#pragma unroll
    for (int rf = 0; rf < 4; ++rf) {
      af[rf][0] = *(const bf16x8*)&smem[bb + arow + rf * 1024 + chunk0];
      af[rf][1] = *(const bf16x8*)&smem[bb + arow + rf * 1024 + chunk1];
    }
#pragma unroll
    for (int cf = 0; cf < 2; ++cf) {
      b0f[cf][0] = *(const bf16x8*)&smem[bb + brow + cf * 1024 + chunk0];
      b0f[cf][1] = *(const bf16x8*)&smem[bb + brow + cf * 1024 + chunk1];
    }
    if (t + 1 < NT64) STAGE(1, t + 1, 0)
    asm volatile("" ::: "memory");
    __builtin_amdgcn_s_barrier();
    __builtin_amdgcn_s_setprio(1);
#pragma unroll
    for (int rf = 0; rf < 4; ++rf)
#pragma unroll
      for (int cf = 0; cf < 2; ++cf)
#pragma unroll
        for (int kh = 0; kh < 2; ++kh)
          acc[rf][cf] = __builtin_amdgcn_mfma_f32_16x16x32_bf16(af[rf][kh], b0f[cf][kh], acc[rf][cf], 0, 0, 0);
    __builtin_amdgcn_s_setprio(0);
    asm volatile("" ::: "memory");
    __builtin_amdgcn_s_barrier();
    // ---- P2: read B-sub1; MFMA (m0,n1) ----
#pragma unroll
    for (int cf = 0; cf < 2; ++cf) {
      b1f[cf][0] = *(const bf16x8*)&smem[bb + brow + 2048 + cf * 1024 + chunk0];
      b1f[cf][1] = *(const bf16x8*)&smem[bb + brow + 2048 + cf * 1024 + chunk1];
    }
    asm volatile("" ::: "memory");
    __builtin_amdgcn_s_barrier();
    __builtin_amdgcn_s_setprio(1);
#pragma unroll
    for (int rf = 0; rf < 4; ++rf)
#pragma unroll
      for (int cf = 0; cf < 2; ++cf)
#pragma unroll
        for (int kh = 0; kh < 2; ++kh)
          acc[rf][2 + cf] = __builtin_amdgcn_mfma_f32_16x16x32_bf16(af[rf][kh], b1f[cf][kh], acc[rf][2 + cf], 0, 0, 0);
    __builtin_amdgcn_s_setprio(0);
    asm volatile("" ::: "memory");
    __builtin_amdgcn_s_barrier();
    // ---- P3: read A(rows wm*128+64..127) (overwrite af); stage B0(t+2); MFMA (m1,n0) ----
#pragma unroll
    for (int rf = 0; rf < 4; ++rf) {
      af[rf][0] = *(const bf16x8*)&smem[bb + arow + 4096 + rf * 1024 + chunk0];
      af[rf][1] = *(const bf16x8*)&smem[bb + arow + 4096 + rf * 1024 + chunk1];
    }
    if (t + 2 < NT64) STAGE(0, t + 2, 1)
    asm volatile("" ::: "memory");
    __builtin_amdgcn_s_barrier();
    __builtin_amdgcn_s_setprio(1);
#pragma unroll
    for (int rf = 0; rf < 4; ++rf)
#pragma unroll
      for (int cf = 0; cf < 2; ++cf)
#pragma unroll
        for (int kh = 0; kh < 2; ++kh)
          acc[4 + rf][cf] = __builtin_amdgcn_mfma_f32_16x16x32_bf16(af[rf][kh], b0f[cf][kh], acc[4 + rf][cf], 0, 0, 0);
    __builtin_amdgcn_s_setprio(0);
    asm volatile("" ::: "memory");
    __builtin_amdgcn_s_barrier();
    // ---- P4: stage A0(t+2)+B1(t+2); MFMA (m1,n1); counted vmcnt; rotate ----
    if (t + 2 < NT64) { STAGE(0, t + 2, 0) STAGE(1, t + 2, 1) }
    asm volatile("" ::: "memory");
    __builtin_amdgcn_s_barrier();
    __builtin_amdgcn_s_setprio(1);
#pragma unroll
    for (int rf = 0; rf < 4; ++rf)
#pragma unroll
      for (int cf = 0; cf < 2; ++cf)
#pragma unroll
        for (int kh = 0; kh < 2; ++kh)
          acc[4 + rf][2 + cf] = __builtin_amdgcn_mfma_f32_16x16x32_bf16(af[rf][kh], b1f[cf][kh], acc[4 + rf][2 + cf], 0, 0, 0);
    __builtin_amdgcn_s_setprio(0);
    if (t < NT64 - 2) asm volatile("s_waitcnt vmcnt(6)" ::: "memory");
    else              asm volatile("s_waitcnt vmcnt(0)" ::: "memory");
    __builtin_amdgcn_s_barrier();
  }

  // ---- epilogue ----
  float bcol[4];
#pragma unroll
  for (int an = 0; an < 4; ++an)
    bcol[an] = biasbase[col0 + wn * 64 + (an >> 1) * 32 + (an & 1) * 16 + lr];

  if (BF16_OUT) {
    unsigned short* wa = &smem[wave * 8192];  // per-wave [128][64] bf16
#pragma unroll
    for (int am = 0; am < 8; ++am) {
      int rbase = (am >> 2) * 64 + (am & 3) * 16 + hi * 4;
#pragma unroll
      for (int j = 0; j < 4; ++j) {
        int r = rbase + j;
        float mrow = mask[row0 + wm * 128 + r];
#pragma unroll
        for (int an = 0; an < 4; ++an) {
          int c = (an >> 1) * 32 + (an & 1) * 16 + lr;
          wa[r * 64 + c] = f2bf((acc[am][an][j] + bcol[an]) * mrow);
        }
      }
    }
    asm volatile("s_waitcnt lgkmcnt(0)" ::: "memory");
    unsigned short* Cg = (unsigned short*)C;
    size_t cbase = (size_t)(row0 + wm * 128) * ldc + col0 + wn * 64;
#pragma unroll
    for (int i = 0; i < 16; ++i) {
      int elem = i * 512 + lane * 8;
      int r = elem >> 6, cc = elem & 63;
      *(uint4*)&Cg[cbase + (size_t)r * ldc + cc] = *(const uint4*)&wa[elem];
    }
  } else {
    float* wf = (float*)&smem[(size_t)wave * 8192];  // per-wave 4096 f32 (16 KB)
    float* Cg = (float*)C;
#pragma unroll
    for (int h = 0; h < 2; ++h) {
#pragma unroll
      for (int am4 = 0; am4 < 4; ++am4) {
        int am = h * 4 + am4;
#pragma unroll
        for (int j = 0; j < 4; ++j) {
          int r = am4 * 16 + hi * 4 + j;
          float mrow = mask[row0 + wm * 128 + h * 64 + r];
#pragma unroll
          for (int an = 0; an < 4; ++an) {
            int c = (an >> 1) * 32 + (an & 1) * 16 + lr;
            wf[r * 64 + c] = (acc[am][an][j] + bcol[an]) * mrow;
          }
        }
      }
      asm volatile("s_waitcnt lgkmcnt(0)" ::: "memory");
#pragma unroll
      for (int i = 0; i < 16; ++i) {
        int e4 = i * 64 + lane;
        int r = e4 >> 4, c4 = e4 & 15;
        *(float4*)&Cg[(size_t)(row0 + wm * 128 + h * 64 + r) * ldc + col0 + wn * 64 + c4 * 4] =
            *(const float4*)&wf[r * 64 + c4 * 4];
      }
      asm volatile("s_waitcnt lgkmcnt(0)" ::: "memory");
    }
  }
#undef STAGE
}

// ---------------- kv = K^T V (split-S partials, deterministic) ----------------
__global__ __launch_bounds__(256) void kvpart_k(const unsigned short* __restrict__ KV,
                                                float* __restrict__ part) {
  int bh = blockIdx.x;  // b*16+h
  int ch = blockIdx.y;
  int b = bh >> 4, h = bh & 15;
  int s0 = ch * (SEQ / NCH);
  const unsigned short* Kp = KV + ((size_t)(b * SEQ + s0)) * 2048 + h * 64;
  const unsigned short* Vp = Kp + 1024;
  __shared__ float ks[32][64], vs[32][64];
  int tid = threadIdx.x;
  int lrow = tid >> 3, lcol = (tid & 7) * 8;
  int ti = tid >> 4, tj = tid & 15;
  float acc[4][4] = {};
  for (int s32 = 0; s32 < SEQ / NCH; s32 += 32) {
    __syncthreads();
    u16x8 k8 = *(const u16x8*)&Kp[(size_t)(s32 + lrow) * 2048 + lcol];
    u16x8 v8 = *(const u16x8*)&Vp[(size_t)(s32 + lrow) * 2048 + lcol];
#pragma unroll
    for (int e = 0; e < 8; ++e) {
      ks[lrow][lcol + e] = bf2f(k8[e]);
      vs[lrow][lcol + e] = bf2f(v8[e]);
    }
    __syncthreads();
#pragma unroll
    for (int ss = 0; ss < 32; ++ss) {
      f32x4 kd = *(const f32x4*)&ks[ss][ti * 4];
      f32x4 ve = *(const f32x4*)&vs[ss][tj * 4];
#pragma unroll
      for (int a = 0; a < 4; ++a)
#pragma unroll
        for (int e = 0; e < 4; ++e) acc[a][e] += kd[a] * ve[e];
    }
  }
  float* dst = part + ((size_t)(ch * 64 + bh)) * 4096 + (ti * 4) * 64 + tj * 4;
#pragma unroll
  for (int a = 0; a < 4; ++a) {
    f32x4 v = {acc[a][0], acc[a][1], acc[a][2], acc[a][3]};
    *(f32x4*)&dst[a * 64] = v;
  }
}

__global__ void kvreduce_k(const float* __restrict__ part, const float* __restrict__ norm,
                           float* __restrict__ kv) {
  int idx = blockIdx.x * 256 + threadIdx.x;
  int b = idx >> 16;
  float s = 0.f;
#pragma unroll
  for (int ch = 0; ch < NCH; ++ch) s += part[(size_t)ch * 262144 + idx];
  kv[idx] = s * norm[b];
}

__global__ void bias2_k(const float* __restrict__ bq, const float* __restrict__ kv,
                        float* __restrict__ bias2) {
  int idx = blockIdx.x * 256 + threadIdx.x;
  int b = idx >> 10, n = idx & 1023, h = n >> 6, e = n & 63;
  const float* kvp = kv + ((size_t)(b * 16 + h)) * 4096 + e;
  float s = 0.f;
#pragma unroll
  for (int d = 0; d < 64; ++d) s += bq[h * 64 + d] * kvp[d * 64];
  bias2[idx] = s;
}

__global__ __launch_bounds__(128) void wprime_k(const float* __restrict__ Wq,
                                                const float* __restrict__ kv,
                                                unsigned short* __restrict__ Wpt) {
  int bh = blockIdx.y, b = bh >> 4, h = bh & 15;
  int c0 = blockIdx.x * 128;
  __shared__ float wqs[128][65];
  __shared__ float kvs[64][64];
  int tid = threadIdx.x;
  for (int i = 0; i < 32; ++i) {
    int idx = i * 128 + tid;
    ((float*)kvs)[idx] = kv[(size_t)bh * 4096 + idx];
  }
  int rr = tid >> 6, cc = tid & 63;
  for (int i = 0; i < 64; ++i) {
    int r = i * 2 + rr;
    wqs[r][cc] = Wq[(size_t)(c0 + r) * HIDDEN + h * 64 + cc];
  }
  __syncthreads();
  float acc[64];
#pragma unroll
  for (int e = 0; e < 64; ++e) acc[e] = 0.f;
  for (int d = 0; d < 64; ++d) {
    float w = wqs[tid][d];
#pragma unroll
    for (int e4 = 0; e4 < 64; e4 += 4) {
      f32x4 kvv = *(const f32x4*)&kvs[d][e4];
      acc[e4 + 0] += w * kvv[0];
      acc[e4 + 1] += w * kvv[1];
      acc[e4 + 2] += w * kvv[2];
      acc[e4 + 3] += w * kvv[3];
    }
  }
  unsigned short* dst = Wpt + (size_t)b * HIDDEN * HIDDEN + (size_t)(h * 64) * HIDDEN + (c0 + tid);
#pragma unroll
  for (int e = 0; e < 64; ++e) dst[(size_t)e * HIDDEN] = f2bf(acc[e]);
}

// ---------------- launch ----------------
extern "C" void kernel_launch(void* const* d_in, const int* in_sizes, int n_in,
                              void* d_out, int out_size, void* d_ws, size_t ws_size,
                              hipStream_t stream) {
  const float* x = (const float*)d_in[0];
  const float* mask = (const float*)d_in[1];
  const float* Wq = (const float*)d_in[2];
  const float* bq = (const float*)d_in[3];
  const float* Wk = (const float*)d_in[4];
  const float* bk = (const float*)d_in[5];
  const float* Wv = (const float*)d_in[6];
  const float* bv = (const float*)d_in[7];
  float* out = (float*)d_out;

  char* w = (char*)d_ws;
  unsigned short* xb = (unsigned short*)w; w += (size_t)M_TOT * HIDDEN * 2;           // 32 MiB
  unsigned short* Bt = (unsigned short*)w; w += (size_t)2048 * HIDDEN * 2;            // 4 MiB
  unsigned short* KV = (unsigned short*)w; w += (size_t)M_TOT * 2048 * 2;             // 64 MiB
  float* part = (float*)w;                 w += (size_t)NCH * 64 * 4096 * 4;          // 16 MiB
  float* kv = (float*)w;                   w += (size_t)64 * 4096 * 4;                // 1 MiB
  unsigned short* Wpt = (unsigned short*)w; w += (size_t)BATCH * HIDDEN * HIDDEN * 2; // 8 MiB
  float* bkv = (float*)w;                  w += 2048 * 4;
  float* bias2 = (float*)w;                w += 4096 * 4;
  float* norm = (float*)w;                 w += 64;

  masksum_k<<<dim3(BATCH), dim3(256), 0, stream>>>(mask, norm);
  convert_x_k<<<dim3(8192), dim3(256), 0, stream>>>(x, xb);
  transw_k<<<dim3(16, 16, 2), dim3(256), 0, stream>>>(Wk, Wv, Bt);
  biascat_k<<<dim3(8), dim3(256), 0, stream>>>(bk, bv, bkv);
  // KV projection: M=16384, N=2048, K=1024 -> grid 64*8=512 blocks
  gemm256_k<1, 0><<<dim3(512), dim3(512), 0, stream>>>(xb, Bt, bkv, mask, (void*)KV, 2048, 8);
  kvpart_k<<<dim3(64, NCH), dim3(256), 0, stream>>>(KV, part);
  kvreduce_k<<<dim3(1024), dim3(256), 0, stream>>>(part, norm, kv);
  bias2_k<<<dim3(16), dim3(256), 0, stream>>>(bq, kv, bias2);
  wprime_k<<<dim3(8, 64), dim3(128), 0, stream>>>(Wq, kv, Wpt);
  // out GEMM: M=16384, N=1024, K=1024 -> grid 64*4=256 blocks
  gemm256_k<0, 1><<<dim3(256), dim3(512), 0, stream>>>(xb, Wpt, bias2, mask, (void*)out, 1024, 4);
}

// Round 5
// 170.128 us; speedup vs baseline: 1.4156x; 1.1769x over previous
//
#include <hip/hip_runtime.h>
#include <stdint.h>

#define HIDDEN 1024
#define SEQ 4096
#define BATCH 4
#define HEADS 16
#define HDIM 64
#define M_TOT (BATCH * SEQ)   // 16384
#define NCH 4                 // split-S chunks for kv reduction
#define NT64 16               // K-steps of 64

typedef __bf16 bf16x8 __attribute__((ext_vector_type(8)));
typedef float f32x4 __attribute__((ext_vector_type(4)));
typedef unsigned short u16x8 __attribute__((ext_vector_type(8)));

static __device__ __forceinline__ unsigned short f2bf(float f) {
  union { float f; uint32_t u; } v; v.f = f;
  uint32_t u = v.u;
  uint32_t r = (u + 0x7fffu + ((u >> 16) & 1u)) >> 16;
  return (unsigned short)r;
}
static __device__ __forceinline__ void load_lds16(const void* g, void* l) {
  __builtin_amdgcn_global_load_lds(
      (__attribute__((address_space(1))) void*)(g),
      (__attribute__((address_space(3))) void*)(l), 16, 0, 0);
}

// ---------------- fused prep kernel ----------------
// blocks [0,8192): x f32 -> bf16
// blocks [8192,8704): Wk/Wv transpose -> Bt bf16
// blocks [8704,8712): bias concat
// blocks [8712,8716): mask sum -> norm
__global__ __launch_bounds__(256) void prep_k(
    const float* __restrict__ x, unsigned short* __restrict__ xb,
    const float* __restrict__ Wk, const float* __restrict__ Wv,
    unsigned short* __restrict__ Bt,
    const float* __restrict__ bk, const float* __restrict__ bv,
    float* __restrict__ bkv,
    const float* __restrict__ mask, float* __restrict__ norm) {
  const int bid = blockIdx.x;
  const int tid = threadIdx.x;
  __shared__ float ts[64][65];
  if (bid < 8192) {
    int idx = bid * 256 + tid;
    const float4* xv = (const float4*)x;
    float4 a = xv[(size_t)idx * 2];
    float4 b = xv[(size_t)idx * 2 + 1];
    u16x8 o;
    o[0] = f2bf(a.x); o[1] = f2bf(a.y); o[2] = f2bf(a.z); o[3] = f2bf(a.w);
    o[4] = f2bf(b.x); o[5] = f2bf(b.y); o[6] = f2bf(b.z); o[7] = f2bf(b.w);
    *(u16x8*)(xb + (size_t)idx * 8) = o;
  } else if (bid < 8704) {
    int idx = bid - 8192;
    int z = idx >> 8, rem = idx & 255;
    const float* W = z ? Wv : Wk;
    unsigned short* out = Bt + (size_t)z * HIDDEN * HIDDEN;
    int n0 = (rem & 15) * 64, k0 = (rem >> 4) * 64;
    int c = tid & 63, rq = tid >> 6;
    for (int i = 0; i < 16; ++i) {
      int r = i * 4 + rq;
      ts[r][c] = W[(size_t)(k0 + r) * HIDDEN + n0 + c];
    }
    __syncthreads();
    for (int i = 0; i < 16; ++i) {
      int n = i * 4 + rq;
      out[(size_t)(n0 + n) * HIDDEN + k0 + c] = f2bf(ts[c][n]);
    }
  } else if (bid < 8712) {
    int i = (bid - 8704) * 256 + tid;
    bkv[i] = (i < HIDDEN) ? bk[i] : bv[i - HIDDEN];
  } else {
    int b = bid - 8712;
    float s = 0.f;
    for (int i = tid; i < SEQ; i += 256) s += mask[b * SEQ + i];
    for (int off = 32; off; off >>= 1) s += __shfl_down(s, off);
    __shared__ float wsum[4];
    if ((tid & 63) == 0) wsum[tid >> 6] = s;
    __syncthreads();
    if (tid == 0) {
      float t = wsum[0] + wsum[1] + wsum[2] + wsum[3];
      norm[b] = rsqrtf(t * (float)HDIM);
    }
  }
}

// ---------------- 256x256 8-phase GEMM (BK=64, dbuf=2, counted vmcnt(6)) ----------
// C[row][n] = sum_k A[row][k]*Bt[n][k] + bias[n], then * mask[row].
// OUT_MODE 0: f32 row-major C[row][n] (ldc).
// OUT_MODE 2: bf16 TRANSPOSED KVt[(n*4+b)*4096 + s]  (b=row0>>12, s=row0&4095).
// Stage schedule (slot-safety proven):
//   P1: A1(t+1) -> buf (t+1)&1 (its A-half1 consumed at P3 of t-1)
//   P3: B0(t+2), B1(t+2) -> buf t&1 (B fully consumed by end of P2)
//   P4: A0(t+2) -> buf t&1 (A-half0 consumed by end of P3)
// End-of-P4 vmcnt(6): 6 newest = {A0,B1,B0}(t+2); forces A1(t+1)+older landed.
template <int OUT_MODE, int PER_BATCH_B>
__global__ __launch_bounds__(512, 2) void gemm256_k(
    const unsigned short* __restrict__ A, const unsigned short* __restrict__ Bt,
    const float* __restrict__ bias, const float* __restrict__ mask,
    void* __restrict__ C, int ldc, int nbn) {
  __shared__ unsigned short smem[65536];  // 128 KiB: 2 bufs x (A 256x64 + B 256x64)

  const int nwg = gridDim.x;
  const int bid = blockIdx.x;
  const int wg = (bid & 7) * (nwg >> 3) + (bid >> 3);  // XCD swizzle (nwg%8==0)
  const int row0 = (wg / nbn) * 256;
  const int col0 = (wg % nbn) * 256;

  const unsigned short* Bbase = Bt;
  const float* biasbase = bias;
  if (PER_BATCH_B) {
    int b = row0 >> 12;
    Bbase = Bt + (size_t)b * HIDDEN * HIDDEN;
    biasbase = bias + b * HIDDEN;
  }

  const int tid = threadIdx.x;
  const int wave = tid >> 6;
  const int lane = tid & 63;
  const int wm = wave >> 2;   // 0..1 (M half)
  const int wn = wave & 3;    // 0..3 (N quarter)
  const int lr = lane & 15;
  const int hi = lane >> 4;   // 0..3

  // staging: linear LDS dest, inverse-swizzled global source (chunk ^= row&7)
  const int srow = tid >> 3;                        // 0..63
  const int scol = ((tid & 7) ^ (srow & 7)) * 8;    // (row&7)-XORed 16B chunk
  const unsigned short* sA = A + (size_t)(row0 + srow) * HIDDEN + scol;
  const unsigned short* sB = Bbase + (size_t)(col0 + srow) * HIDDEN + scol;
  const int ldst = tid * 8;

#define STAGE(half, tt, isB) { \
    int dst_ = ((tt)&1) * 32768 + (isB) * 16384 + (half) * 8192 + ldst; \
    const unsigned short* src_ = ((isB) ? sB : sA) + (size_t)(half) * 128 * HIDDEN + (tt) * 64; \
    load_lds16(src_, &smem[dst_]); \
    load_lds16(src_ + (size_t)64 * HIDDEN, &smem[dst_ + 4096]); }

  // swizzled frag read offsets: row ra -> ra*64 + ((k8 ^ (ra&7))*8); ra&7 == lr&7
  const int chunk0 = (hi ^ (lr & 7)) * 8;          // kh=0
  const int chunk1 = ((4 + hi) ^ (lr & 7)) * 8;    // kh=1
  const int arow = (wm * 128 + lr) * 64;           // + rf*1024 (+4096 for m-half 1)
  const int brow = 16384 + (wn * 64 + lr) * 64;    // + cf*1024 (+2048 for n-sub 1)

  f32x4 acc[8][4];
#pragma unroll
  for (int i = 0; i < 8; ++i)
#pragma unroll
    for (int j = 0; j < 4; ++j) acc[i][j] = (f32x4){0.f, 0.f, 0.f, 0.f};

  // prologue: K0 full + A0,B0,B1 of K1 (14 loads); oldest 8 (=K0) must land
  STAGE(0, 0, 0) STAGE(0, 0, 1) STAGE(1, 0, 1) STAGE(1, 0, 0)
  STAGE(0, 1, 0) STAGE(0, 1, 1) STAGE(1, 1, 1)
  asm volatile("s_waitcnt vmcnt(6)" ::: "memory");
  __builtin_amdgcn_s_barrier();

  bf16x8 af[4][2], b0f[2][2], b1f[2][2];
  for (int t = 0; t < NT64; ++t) {
    const int bb = (t & 1) * 32768;
    // ---- P1: read A(rows wm*128+0..63) + B-sub0; stage A1(t+1); MFMA (m0,n0) ----
#pragma unroll
    for (int rf = 0; rf < 4; ++rf) {
      af[rf][0] = *(const bf16x8*)&smem[bb + arow + rf * 1024 + chunk0];
      af[rf][1] = *(const bf16x8*)&smem[bb + arow + rf * 1024 + chunk1];
    }
#pragma unroll
    for (int cf = 0; cf < 2; ++cf) {
      b0f[cf][0] = *(const bf16x8*)&smem[bb + brow + cf * 1024 + chunk0];
      b0f[cf][1] = *(const bf16x8*)&smem[bb + brow + cf * 1024 + chunk1];
    }
    if (t + 1 < NT64) STAGE(1, t + 1, 0)
    asm volatile("" ::: "memory");
    __builtin_amdgcn_s_barrier();
    __builtin_amdgcn_s_setprio(1);
#pragma unroll
    for (int rf = 0; rf < 4; ++rf)
#pragma unroll
      for (int cf = 0; cf < 2; ++cf)
#pragma unroll
        for (int kh = 0; kh < 2; ++kh)
          acc[rf][cf] = __builtin_amdgcn_mfma_f32_16x16x32_bf16(af[rf][kh], b0f[cf][kh], acc[rf][cf], 0, 0, 0);
    __builtin_amdgcn_s_setprio(0);
    asm volatile("" ::: "memory");
    __builtin_amdgcn_s_barrier();
    // ---- P2: read B-sub1; MFMA (m0,n1) ----
#pragma unroll
    for (int cf = 0; cf < 2; ++cf) {
      b1f[cf][0] = *(const bf16x8*)&smem[bb + brow + 2048 + cf * 1024 + chunk0];
      b1f[cf][1] = *(const bf16x8*)&smem[bb + brow + 2048 + cf * 1024 + chunk1];
    }
    asm volatile("" ::: "memory");
    __builtin_amdgcn_s_barrier();
    __builtin_amdgcn_s_setprio(1);
#pragma unroll
    for (int rf = 0; rf < 4; ++rf)
#pragma unroll
      for (int cf = 0; cf < 2; ++cf)
#pragma unroll
        for (int kh = 0; kh < 2; ++kh)
          acc[rf][2 + cf] = __builtin_amdgcn_mfma_f32_16x16x32_bf16(af[rf][kh], b1f[cf][kh], acc[rf][2 + cf], 0, 0, 0);
    __builtin_amdgcn_s_setprio(0);
    asm volatile("" ::: "memory");
    __builtin_amdgcn_s_barrier();
    // ---- P3: read A(rows wm*128+64..127); stage B0(t+2)+B1(t+2); MFMA (m1,n0) ----
#pragma unroll
    for (int rf = 0; rf < 4; ++rf) {
      af[rf][0] = *(const bf16x8*)&smem[bb + arow + 4096 + rf * 1024 + chunk0];
      af[rf][1] = *(const bf16x8*)&smem[bb + arow + 4096 + rf * 1024 + chunk1];
    }
    if (t + 2 < NT64) { STAGE(0, t + 2, 1) STAGE(1, t + 2, 1) }
    asm volatile("" ::: "memory");
    __builtin_amdgcn_s_barrier();
    __builtin_amdgcn_s_setprio(1);
#pragma unroll
    for (int rf = 0; rf < 4; ++rf)
#pragma unroll
      for (int cf = 0; cf < 2; ++cf)
#pragma unroll
        for (int kh = 0; kh < 2; ++kh)
          acc[4 + rf][cf] = __builtin_amdgcn_mfma_f32_16x16x32_bf16(af[rf][kh], b0f[cf][kh], acc[4 + rf][cf], 0, 0, 0);
    __builtin_amdgcn_s_setprio(0);
    asm volatile("" ::: "memory");
    __builtin_amdgcn_s_barrier();
    // ---- P4: stage A0(t+2); MFMA (m1,n1); counted vmcnt; rotate ----
    if (t + 2 < NT64) STAGE(0, t + 2, 0)
    asm volatile("" ::: "memory");
    __builtin_amdgcn_s_barrier();
    __builtin_amdgcn_s_setprio(1);
#pragma unroll
    for (int rf = 0; rf < 4; ++rf)
#pragma unroll
      for (int cf = 0; cf < 2; ++cf)
#pragma unroll
        for (int kh = 0; kh < 2; ++kh)
          acc[4 + rf][2 + cf] = __builtin_amdgcn_mfma_f32_16x16x32_bf16(af[rf][kh], b1f[cf][kh], acc[4 + rf][2 + cf], 0, 0, 0);
    __builtin_amdgcn_s_setprio(0);
    if (t < NT64 - 2) asm volatile("s_waitcnt vmcnt(6)" ::: "memory");
    else              asm volatile("s_waitcnt vmcnt(0)" ::: "memory");
    __builtin_amdgcn_s_barrier();
  }

  // ---- epilogue ----
  float bcol[4];
#pragma unroll
  for (int an = 0; an < 4; ++an)
    bcol[an] = biasbase[col0 + wn * 64 + (an >> 1) * 32 + (an & 1) * 16 + lr];

  if (OUT_MODE == 2) {
    // transposed bf16 store: KVt[(n*4+b)*4096 + s]
    const int b = row0 >> 12;
    const int s0 = (row0 & 4095) + wm * 128;
    unsigned short* wt = &smem[wave * 4096];  // 8 KB/wave region (elems)
    unsigned short* KVt = (unsigned short*)C;
#pragma unroll
    for (int half = 0; half < 2; ++half) {
#pragma unroll
      for (int am4 = 0; am4 < 4; ++am4) {
#pragma unroll
        for (int j = 0; j < 4; ++j) {
          int r = am4 * 16 + hi * 4 + j;  // 0..63 within half
          float mrow = mask[row0 + wm * 128 + half * 64 + r];
#pragma unroll
          for (int an = 0; an < 4; ++an) {
            int c = (an >> 1) * 32 + (an & 1) * 16 + lr;
            wt[c * 64 + (r ^ ((c & 7) << 3))] =
                f2bf((acc[half * 4 + am4][an][j] + bcol[an]) * mrow);
          }
        }
      }
      asm volatile("s_waitcnt lgkmcnt(0)" ::: "memory");
#pragma unroll
      for (int i = 0; i < 8; ++i) {
        int flat = i * 64 + lane;
        int c = flat >> 3, rq = flat & 7;
        uint4 vv = *(const uint4*)&wt[c * 64 + ((rq * 8) ^ ((c & 7) << 3))];
        *(uint4*)&KVt[((size_t)(col0 + wn * 64 + c) * 4 + b) * 4096 + s0 + half * 64 + rq * 8] = vv;
      }
      asm volatile("s_waitcnt lgkmcnt(0)" ::: "memory");
    }
  } else {
    float* wf = (float*)&smem[(size_t)wave * 8192];  // per-wave 4096 f32 (16 KB)
    float* Cg = (float*)C;
#pragma unroll
    for (int h = 0; h < 2; ++h) {
#pragma unroll
      for (int am4 = 0; am4 < 4; ++am4) {
        int am = h * 4 + am4;
#pragma unroll
        for (int j = 0; j < 4; ++j) {
          int r = am4 * 16 + hi * 4 + j;
          float mrow = mask[row0 + wm * 128 + h * 64 + r];
#pragma unroll
          for (int an = 0; an < 4; ++an) {
            int c = (an >> 1) * 32 + (an & 1) * 16 + lr;
            wf[r * 64 + c] = (acc[am][an][j] + bcol[an]) * mrow;
          }
        }
      }
      asm volatile("s_waitcnt lgkmcnt(0)" ::: "memory");
#pragma unroll
      for (int i = 0; i < 16; ++i) {
        int e4 = i * 64 + lane;
        int r = e4 >> 4, c4 = e4 & 15;
        *(float4*)&Cg[(size_t)(row0 + wm * 128 + h * 64 + r) * ldc + col0 + wn * 64 + c4 * 4] =
            *(const float4*)&wf[r * 64 + c4 * 4];
      }
      asm volatile("s_waitcnt lgkmcnt(0)" ::: "memory");
    }
  }
#undef STAGE
}

// ---------------- kv partials via MFMA: part[ch][bh][d][e] = sum_s Kt[d][s]*Vt[e][s] ----
__global__ __launch_bounds__(256) void kvpart2_k(const unsigned short* __restrict__ KVt,
                                                 float* __restrict__ part) {
  const int bh = blockIdx.x, ch = blockIdx.y;
  const int b = bh >> 4, h = bh & 15;
  __shared__ unsigned short tl[32768];  // 4 bufs x (A[64][64] + B[64][64]) = 64 KiB
  const int tid = threadIdx.x;
  const int wave = tid >> 6, lane = tid & 63;
  const int lr = lane & 15, hi = lane >> 4;

  const int r0 = tid >> 3;
  const int cc0 = ((tid & 7) ^ (r0 & 7)) * 8;
  const int r1 = 32 + r0;
  const int cc1 = ((tid & 7) ^ (r1 & 7)) * 8;
  const unsigned short* A0 = KVt + ((size_t)(h * 64 + r0) * 4 + b) * 4096 + ch * 1024 + cc0;
  const unsigned short* A1 = KVt + ((size_t)(h * 64 + r1) * 4 + b) * 4096 + ch * 1024 + cc1;
  const unsigned short* B0 = KVt + ((size_t)(1024 + h * 64 + r0) * 4 + b) * 4096 + ch * 1024 + cc0;
  const unsigned short* B1 = KVt + ((size_t)(1024 + h * 64 + r1) * 4 + b) * 4096 + ch * 1024 + cc1;

#define KSTAGE(tt) { int bb2 = ((tt) & 3) * 8192; \
    load_lds16(A0 + (tt) * 64, &tl[bb2 + tid * 8]); \
    load_lds16(A1 + (tt) * 64, &tl[bb2 + 2048 + tid * 8]); \
    load_lds16(B0 + (tt) * 64, &tl[bb2 + 4096 + tid * 8]); \
    load_lds16(B1 + (tt) * 64, &tl[bb2 + 6144 + tid * 8]); }

  const int ra = wave * 16 + lr;
  const int aoff = ra * 64;
  const int ach0 = (hi ^ (ra & 7)) * 8, ach1 = ((4 + hi) ^ (ra & 7)) * 8;

  f32x4 acc4[4];
#pragma unroll
  for (int nt = 0; nt < 4; ++nt) acc4[nt] = (f32x4){0.f, 0.f, 0.f, 0.f};

  KSTAGE(0) KSTAGE(1)
  asm volatile("s_waitcnt vmcnt(4)" ::: "memory");
  __builtin_amdgcn_s_barrier();
  for (int t = 0; t < 16; ++t) {
    const int bb = (t & 3) * 8192;
    if (t + 2 < 16) KSTAGE(t + 2)
    bf16x8 a0 = *(const bf16x8*)&tl[bb + aoff + ach0];
    bf16x8 a1 = *(const bf16x8*)&tl[bb + aoff + ach1];
    bf16x8 bf0[4], bf1[4];
#pragma unroll
    for (int nt = 0; nt < 4; ++nt) {
      int rb = nt * 16 + lr;
      bf0[nt] = *(const bf16x8*)&tl[bb + 4096 + rb * 64 + ((hi ^ (rb & 7)) * 8)];
      bf1[nt] = *(const bf16x8*)&tl[bb + 4096 + rb * 64 + (((4 + hi) ^ (rb & 7)) * 8)];
    }
#pragma unroll
    for (int nt = 0; nt < 4; ++nt) {
      acc4[nt] = __builtin_amdgcn_mfma_f32_16x16x32_bf16(a0, bf0[nt], acc4[nt], 0, 0, 0);
      acc4[nt] = __builtin_amdgcn_mfma_f32_16x16x32_bf16(a1, bf1[nt], acc4[nt], 0, 0, 0);
    }
    if (t < 14) asm volatile("s_waitcnt vmcnt(4)" ::: "memory");
    else        asm volatile("s_waitcnt vmcnt(0)" ::: "memory");
    __builtin_amdgcn_s_barrier();
  }
  float* dst = part + ((size_t)ch * 64 + bh) * 4096;
#pragma unroll
  for (int nt = 0; nt < 4; ++nt)
#pragma unroll
    for (int j = 0; j < 4; ++j)
      dst[(wave * 16 + hi * 4 + j) * 64 + nt * 16 + lr] = acc4[nt][j];
#undef KSTAGE
}

// kv[bh*4096 + d*64 + e] = norm[b] * sum_ch part  (grid 1024 x 256)
__global__ void kvreduce_k(const float* __restrict__ part, const float* __restrict__ norm,
                           float* __restrict__ kv) {
  int idx = blockIdx.x * 256 + threadIdx.x;
  int b = idx >> 16;
  float s = 0.f;
#pragma unroll
  for (int ch = 0; ch < NCH; ++ch) s += part[(size_t)ch * 262144 + idx];
  kv[idx] = s * norm[b];
}

__global__ void bias2_k(const float* __restrict__ bq, const float* __restrict__ kv,
                        float* __restrict__ bias2) {
  int idx = blockIdx.x * 256 + threadIdx.x;
  int b = idx >> 10, n = idx & 1023, h = n >> 6, e = n & 63;
  const float* kvp = kv + ((size_t)(b * 16 + h)) * 4096 + e;
  float s = 0.f;
#pragma unroll
  for (int d = 0; d < 64; ++d) s += bq[h * 64 + d] * kvp[d * 64];
  bias2[idx] = s;
}

__global__ __launch_bounds__(128) void wprime_k(const float* __restrict__ Wq,
                                                const float* __restrict__ kv,
                                                unsigned short* __restrict__ Wpt) {
  int bh = blockIdx.y, b = bh >> 4, h = bh & 15;
  int c0 = blockIdx.x * 128;
  __shared__ float wqs[128][65];
  __shared__ float kvs[64][64];
  int tid = threadIdx.x;
  for (int i = 0; i < 32; ++i) {
    int idx = i * 128 + tid;
    ((float*)kvs)[idx] = kv[(size_t)bh * 4096 + idx];
  }
  int rr = tid >> 6, cc = tid & 63;
  for (int i = 0; i < 64; ++i) {
    int r = i * 2 + rr;
    wqs[r][cc] = Wq[(size_t)(c0 + r) * HIDDEN + h * 64 + cc];
  }
  __syncthreads();
  float acc[64];
#pragma unroll
  for (int e = 0; e < 64; ++e) acc[e] = 0.f;
  for (int d = 0; d < 64; ++d) {
    float w = wqs[tid][d];
#pragma unroll
    for (int e4 = 0; e4 < 64; e4 += 4) {
      f32x4 kvv = *(const f32x4*)&kvs[d][e4];
      acc[e4 + 0] += w * kvv[0];
      acc[e4 + 1] += w * kvv[1];
      acc[e4 + 2] += w * kvv[2];
      acc[e4 + 3] += w * kvv[3];
    }
  }
  unsigned short* dst = Wpt + (size_t)b * HIDDEN * HIDDEN + (size_t)(h * 64) * HIDDEN + (c0 + tid);
#pragma unroll
  for (int e = 0; e < 64; ++e) dst[(size_t)e * HIDDEN] = f2bf(acc[e]);
}

// ---------------- launch ----------------
extern "C" void kernel_launch(void* const* d_in, const int* in_sizes, int n_in,
                              void* d_out, int out_size, void* d_ws, size_t ws_size,
                              hipStream_t stream) {
  const float* x = (const float*)d_in[0];
  const float* mask = (const float*)d_in[1];
  const float* Wq = (const float*)d_in[2];
  const float* bq = (const float*)d_in[3];
  const float* Wk = (const float*)d_in[4];
  const float* bk = (const float*)d_in[5];
  const float* Wv = (const float*)d_in[6];
  const float* bv = (const float*)d_in[7];
  float* out = (float*)d_out;

  char* w = (char*)d_ws;
  unsigned short* xb = (unsigned short*)w;  w += (size_t)M_TOT * HIDDEN * 2;           // 32 MiB
  unsigned short* Bt = (unsigned short*)w;  w += (size_t)2048 * HIDDEN * 2;            // 4 MiB
  unsigned short* KVt = (unsigned short*)w; w += (size_t)2048 * BATCH * SEQ * 2;       // 64 MiB
  float* part = (float*)w;                  w += (size_t)NCH * 64 * 4096 * 4;          // 4 MiB
  float* kv = (float*)w;                    w += (size_t)64 * 4096 * 4;                // 1 MiB
  unsigned short* Wpt = (unsigned short*)w; w += (size_t)BATCH * HIDDEN * HIDDEN * 2;  // 8 MiB
  float* bkv = (float*)w;                   w += 2048 * 4;
  float* bias2 = (float*)w;                 w += 4096 * 4;
  float* norm = (float*)w;                  w += 64;

  prep_k<<<dim3(8716), dim3(256), 0, stream>>>(x, xb, Wk, Wv, Bt, bk, bv, bkv, mask, norm);
  // KV projection: M=16384, N=2048, K=1024 -> 512 blocks; writes transposed KVt
  gemm256_k<2, 0><<<dim3(512), dim3(512), 0, stream>>>(xb, Bt, bkv, mask, (void*)KVt, 0, 8);
  kvpart2_k<<<dim3(64, NCH), dim3(256), 0, stream>>>(KVt, part);
  kvreduce_k<<<dim3(1024), dim3(256), 0, stream>>>(part, norm, kv);
  bias2_k<<<dim3(16), dim3(256), 0, stream>>>(bq, kv, bias2);
  wprime_k<<<dim3(8, 64), dim3(128), 0, stream>>>(Wq, kv, Wpt);
  // out GEMM: M=16384, N=1024, K=1024 -> 256 blocks; f32 out
  gemm256_k<0, 1><<<dim3(256), dim3(512), 0, stream>>>(xb, Wpt, bias2, mask, (void*)out, 1024, 4);
}

// Round 6
// 168.594 us; speedup vs baseline: 1.4285x; 1.0091x over previous
//
#include <hip/hip_runtime.h>
#include <stdint.h>

#define HIDDEN 1024
#define SEQ 4096
#define BATCH 4
#define HEADS 16
#define HDIM 64
#define M_TOT (BATCH * SEQ)   // 16384
#define NCH 4                 // split-S chunks for kv reduction
#define NT64 16               // K-steps of 64

typedef __bf16 bf16x8 __attribute__((ext_vector_type(8)));
typedef float f32x4 __attribute__((ext_vector_type(4)));
typedef unsigned short u16x8 __attribute__((ext_vector_type(8)));

static __device__ __forceinline__ unsigned short f2bf(float f) {
  union { float f; uint32_t u; } v; v.f = f;
  uint32_t u = v.u;
  uint32_t r = (u + 0x7fffu + ((u >> 16) & 1u)) >> 16;
  return (unsigned short)r;
}
static __device__ __forceinline__ void load_lds16(const void* g, void* l) {
  __builtin_amdgcn_global_load_lds(
      (__attribute__((address_space(1))) void*)(g),
      (__attribute__((address_space(3))) void*)(l), 16, 0, 0);
}

// ---------------- fused prep kernel ----------------
__global__ __launch_bounds__(256) void prep_k(
    const float* __restrict__ x, unsigned short* __restrict__ xb,
    const float* __restrict__ Wk, const float* __restrict__ Wv,
    unsigned short* __restrict__ Bt,
    const float* __restrict__ bk, const float* __restrict__ bv,
    float* __restrict__ bkv,
    const float* __restrict__ mask, float* __restrict__ norm) {
  const int bid = blockIdx.x;
  const int tid = threadIdx.x;
  __shared__ float ts[64][65];
  if (bid < 8192) {
    int idx = bid * 256 + tid;
    const float4* xv = (const float4*)x;
    float4 a = xv[(size_t)idx * 2];
    float4 b = xv[(size_t)idx * 2 + 1];
    u16x8 o;
    o[0] = f2bf(a.x); o[1] = f2bf(a.y); o[2] = f2bf(a.z); o[3] = f2bf(a.w);
    o[4] = f2bf(b.x); o[5] = f2bf(b.y); o[6] = f2bf(b.z); o[7] = f2bf(b.w);
    *(u16x8*)(xb + (size_t)idx * 8) = o;
  } else if (bid < 8704) {
    int idx = bid - 8192;
    int z = idx >> 8, rem = idx & 255;
    const float* W = z ? Wv : Wk;
    unsigned short* out = Bt + (size_t)z * HIDDEN * HIDDEN;
    int n0 = (rem & 15) * 64, k0 = (rem >> 4) * 64;
    int c = tid & 63, rq = tid >> 6;
    for (int i = 0; i < 16; ++i) {
      int r = i * 4 + rq;
      ts[r][c] = W[(size_t)(k0 + r) * HIDDEN + n0 + c];
    }
    __syncthreads();
    for (int i = 0; i < 16; ++i) {
      int n = i * 4 + rq;
      out[(size_t)(n0 + n) * HIDDEN + k0 + c] = f2bf(ts[c][n]);
    }
  } else if (bid < 8712) {
    int i = (bid - 8704) * 256 + tid;
    bkv[i] = (i < HIDDEN) ? bk[i] : bv[i - HIDDEN];
  } else {
    int b = bid - 8712;
    float s = 0.f;
    for (int i = tid; i < SEQ; i += 256) s += mask[b * SEQ + i];
    for (int off = 32; off; off >>= 1) s += __shfl_down(s, off);
    __shared__ float wsum[4];
    if ((tid & 63) == 0) wsum[tid >> 6] = s;
    __syncthreads();
    if (tid == 0) {
      float t = wsum[0] + wsum[1] + wsum[2] + wsum[3];
      norm[b] = rsqrtf(t * (float)HDIM);
    }
  }
}

// ---------------- 256x256 GEMM: 4 phases/K-tile, ONE barrier per phase ----------
// C[row][n] = sum_k A[row][k]*Bt[n][k] + bias[n], then * mask[row].
// OUT_MODE 0: f32 row-major C. OUT_MODE 2: bf16 transposed KVt[(n*4+b)*4096+s].
// Region liveness (buf t&1): A-half0 read P1,P3(wm=0); A-half1 read P1,P3(wm=1);
// B-half0 read P1,P2(wn=0,1); B-half1 read P1,P2(wn=2,3).
// Stage slots (all dead >=2 phases at write, safe at drift<=1 phase):
//   P1(t): A0(t+1) -> buf(t+1)&1 (last read P3(t-1), 2 phases earlier)
//   P2(t): A1(t+1) -> buf(t+1)&1 (last read P3(t-1), 3 phases earlier)
//   P4(t): B0+B1(t+2) -> buf t&1 (last read P2(t), 2 phases earlier)
// End-of-P4(t) vmcnt(4): outstanding {A0(t+1),A1(t+1),B(t+2)x4}=8; retire 4 oldest
// => A0,A1(t+1) landed; B(t+1) landed since P4(t-1)'s vmcnt. Leaves B(t+2) in flight.
template <int OUT_MODE, int PER_BATCH_B>
__global__ __launch_bounds__(512, 2) void gemm256_k(
    const unsigned short* __restrict__ A, const unsigned short* __restrict__ Bt,
    const float* __restrict__ bias, const float* __restrict__ mask,
    void* __restrict__ C, int ldc, int nbn) {
  __shared__ unsigned short smem[65536];  // 128 KiB: 2 bufs x (A 256x64 + B 256x64)

  const int nwg = gridDim.x;
  const int bid = blockIdx.x;
  const int wg = (bid & 7) * (nwg >> 3) + (bid >> 3);  // XCD swizzle (nwg%8==0)
  const int row0 = (wg / nbn) * 256;
  const int col0 = (wg % nbn) * 256;

  const unsigned short* Bbase = Bt;
  const float* biasbase = bias;
  if (PER_BATCH_B) {
    int b = row0 >> 12;
    Bbase = Bt + (size_t)b * HIDDEN * HIDDEN;
    biasbase = bias + b * HIDDEN;
  }

  const int tid = threadIdx.x;
  const int wave = tid >> 6;
  const int lane = tid & 63;
  const int wm = wave >> 2;   // 0..1 (M half)
  const int wn = wave & 3;    // 0..3 (N quarter)
  const int lr = lane & 15;
  const int hi = lane >> 4;   // 0..3

  // staging: linear LDS dest, inverse-swizzled global source (chunk ^= row&7)
  const int srow = tid >> 3;                        // 0..63
  const int scol = ((tid & 7) ^ (srow & 7)) * 8;    // (row&7)-XORed 16B chunk
  const unsigned short* sA = A + (size_t)(row0 + srow) * HIDDEN + scol;
  const unsigned short* sB = Bbase + (size_t)(col0 + srow) * HIDDEN + scol;
  const int ldst = tid * 8;

#define STAGE(half, tt, isB) { \
    int dst_ = ((tt)&1) * 32768 + (isB) * 16384 + (half) * 8192 + ldst; \
    const unsigned short* src_ = ((isB) ? sB : sA) + (size_t)(half) * 128 * HIDDEN + (tt) * 64; \
    load_lds16(src_, &smem[dst_]); \
    load_lds16(src_ + (size_t)64 * HIDDEN, &smem[dst_ + 4096]); }

  // swizzled frag read offsets: row ra -> ra*64 + ((k8 ^ (ra&7))*8); ra&7 == lr&7
  const int chunk0 = (hi ^ (lr & 7)) * 8;          // kh=0
  const int chunk1 = ((4 + hi) ^ (lr & 7)) * 8;    // kh=1
  const int arow = (wm * 128 + lr) * 64;           // + rf*1024 (+4096 for q3)
  const int brow = 16384 + (wn * 64 + lr) * 64;    // + cf*1024 (+2048 for n-sub 1)

  f32x4 acc[8][4];
#pragma unroll
  for (int i = 0; i < 8; ++i)
#pragma unroll
    for (int j = 0; j < 4; ++j) acc[i][j] = (f32x4){0.f, 0.f, 0.f, 0.f};

  // prologue: t0 full (8 loads) + B(1) (4 loads); vmcnt(4) => t0 landed
  STAGE(0, 0, 0) STAGE(1, 0, 0) STAGE(0, 0, 1) STAGE(1, 0, 1)
  STAGE(0, 1, 1) STAGE(1, 1, 1)
  asm volatile("s_waitcnt vmcnt(4)" ::: "memory");
  __builtin_amdgcn_s_barrier();

  bf16x8 af[4][2], b0f[2][2], b1f[2][2];
  for (int t = 0; t < NT64; ++t) {
    const int bb = (t & 1) * 32768;
    // ---- P1: ds_read A-quad1 + B-sub0; stage A0(t+1); MFMA (m0,n0); barrier ----
#pragma unroll
    for (int rf = 0; rf < 4; ++rf) {
      af[rf][0] = *(const bf16x8*)&smem[bb + arow + rf * 1024 + chunk0];
      af[rf][1] = *(const bf16x8*)&smem[bb + arow + rf * 1024 + chunk1];
    }
#pragma unroll
    for (int cf = 0; cf < 2; ++cf) {
      b0f[cf][0] = *(const bf16x8*)&smem[bb + brow + cf * 1024 + chunk0];
      b0f[cf][1] = *(const bf16x8*)&smem[bb + brow + cf * 1024 + chunk1];
    }
    if (t + 1 < NT64) STAGE(0, t + 1, 0)
    __builtin_amdgcn_s_setprio(1);
#pragma unroll
    for (int rf = 0; rf < 4; ++rf)
#pragma unroll
      for (int cf = 0; cf < 2; ++cf)
#pragma unroll
        for (int kh = 0; kh < 2; ++kh)
          acc[rf][cf] = __builtin_amdgcn_mfma_f32_16x16x32_bf16(af[rf][kh], b0f[cf][kh], acc[rf][cf], 0, 0, 0);
    __builtin_amdgcn_s_setprio(0);
    asm volatile("" ::: "memory");
    __builtin_amdgcn_s_barrier();
    // ---- P2: ds_read B-sub1; stage A1(t+1); MFMA (m0,n1); barrier ----
#pragma unroll
    for (int cf = 0; cf < 2; ++cf) {
      b1f[cf][0] = *(const bf16x8*)&smem[bb + brow + 2048 + cf * 1024 + chunk0];
      b1f[cf][1] = *(const bf16x8*)&smem[bb + brow + 2048 + cf * 1024 + chunk1];
    }
    if (t + 1 < NT64) STAGE(1, t + 1, 0)
    __builtin_amdgcn_s_setprio(1);
#pragma unroll
    for (int rf = 0; rf < 4; ++rf)
#pragma unroll
      for (int cf = 0; cf < 2; ++cf)
#pragma unroll
        for (int kh = 0; kh < 2; ++kh)
          acc[rf][2 + cf] = __builtin_amdgcn_mfma_f32_16x16x32_bf16(af[rf][kh], b1f[cf][kh], acc[rf][2 + cf], 0, 0, 0);
    __builtin_amdgcn_s_setprio(0);
    asm volatile("" ::: "memory");
    __builtin_amdgcn_s_barrier();
    // ---- P3: ds_read A-quad3; MFMA (m1,n0); barrier ----
#pragma unroll
    for (int rf = 0; rf < 4; ++rf) {
      af[rf][0] = *(const bf16x8*)&smem[bb + arow + 4096 + rf * 1024 + chunk0];
      af[rf][1] = *(const bf16x8*)&smem[bb + arow + 4096 + rf * 1024 + chunk1];
    }
    __builtin_amdgcn_s_setprio(1);
#pragma unroll
    for (int rf = 0; rf < 4; ++rf)
#pragma unroll
      for (int cf = 0; cf < 2; ++cf)
#pragma unroll
        for (int kh = 0; kh < 2; ++kh)
          acc[4 + rf][cf] = __builtin_amdgcn_mfma_f32_16x16x32_bf16(af[rf][kh], b0f[cf][kh], acc[4 + rf][cf], 0, 0, 0);
    __builtin_amdgcn_s_setprio(0);
    asm volatile("" ::: "memory");
    __builtin_amdgcn_s_barrier();
    // ---- P4: stage B0+B1(t+2); MFMA (m1,n1); counted vmcnt; barrier ----
    if (t + 2 < NT64) { STAGE(0, t + 2, 1) STAGE(1, t + 2, 1) }
    __builtin_amdgcn_s_setprio(1);
#pragma unroll
    for (int rf = 0; rf < 4; ++rf)
#pragma unroll
      for (int cf = 0; cf < 2; ++cf)
#pragma unroll
        for (int kh = 0; kh < 2; ++kh)
          acc[4 + rf][2 + cf] = __builtin_amdgcn_mfma_f32_16x16x32_bf16(af[rf][kh], b1f[cf][kh], acc[4 + rf][2 + cf], 0, 0, 0);
    __builtin_amdgcn_s_setprio(0);
    if (t < NT64 - 3) asm volatile("s_waitcnt vmcnt(4)" ::: "memory");
    else              asm volatile("s_waitcnt vmcnt(0)" ::: "memory");
    __builtin_amdgcn_s_barrier();
  }

  // ---- epilogue ----
  float bcol[4];
#pragma unroll
  for (int an = 0; an < 4; ++an)
    bcol[an] = biasbase[col0 + wn * 64 + (an >> 1) * 32 + (an & 1) * 16 + lr];

  if (OUT_MODE == 2) {
    // transposed bf16 store: KVt[(n*4+b)*4096 + s]
    const int b = row0 >> 12;
    const int s0 = (row0 & 4095) + wm * 128;
    unsigned short* wt = &smem[wave * 4096];
    unsigned short* KVt = (unsigned short*)C;
#pragma unroll
    for (int half = 0; half < 2; ++half) {
#pragma unroll
      for (int am4 = 0; am4 < 4; ++am4) {
#pragma unroll
        for (int j = 0; j < 4; ++j) {
          int r = am4 * 16 + hi * 4 + j;  // 0..63 within half
          float mrow = mask[row0 + wm * 128 + half * 64 + r];
#pragma unroll
          for (int an = 0; an < 4; ++an) {
            int c = (an >> 1) * 32 + (an & 1) * 16 + lr;
            wt[c * 64 + (r ^ ((c & 7) << 3))] =
                f2bf((acc[half * 4 + am4][an][j] + bcol[an]) * mrow);
          }
        }
      }
      asm volatile("s_waitcnt lgkmcnt(0)" ::: "memory");
#pragma unroll
      for (int i = 0; i < 8; ++i) {
        int flat = i * 64 + lane;
        int c = flat >> 3, rq = flat & 7;
        uint4 vv = *(const uint4*)&wt[c * 64 + ((rq * 8) ^ ((c & 7) << 3))];
        *(uint4*)&KVt[((size_t)(col0 + wn * 64 + c) * 4 + b) * 4096 + s0 + half * 64 + rq * 8] = vv;
      }
      asm volatile("s_waitcnt lgkmcnt(0)" ::: "memory");
    }
  } else {
    float* wf = (float*)&smem[(size_t)wave * 8192];
    float* Cg = (float*)C;
#pragma unroll
    for (int h = 0; h < 2; ++h) {
#pragma unroll
      for (int am4 = 0; am4 < 4; ++am4) {
        int am = h * 4 + am4;
#pragma unroll
        for (int j = 0; j < 4; ++j) {
          int r = am4 * 16 + hi * 4 + j;
          float mrow = mask[row0 + wm * 128 + h * 64 + r];
#pragma unroll
          for (int an = 0; an < 4; ++an) {
            int c = (an >> 1) * 32 + (an & 1) * 16 + lr;
            wf[r * 64 + c] = (acc[am][an][j] + bcol[an]) * mrow;
          }
        }
      }
      asm volatile("s_waitcnt lgkmcnt(0)" ::: "memory");
#pragma unroll
      for (int i = 0; i < 16; ++i) {
        int e4 = i * 64 + lane;
        int r = e4 >> 4, c4 = e4 & 15;
        *(float4*)&Cg[(size_t)(row0 + wm * 128 + h * 64 + r) * ldc + col0 + wn * 64 + c4 * 4] =
            *(const float4*)&wf[r * 64 + c4 * 4];
      }
      asm volatile("s_waitcnt lgkmcnt(0)" ::: "memory");
    }
  }
#undef STAGE
}

// ---------------- kv partials via MFMA: part[ch][bh][d][e] = sum_s Kt[d][s]*Vt[e][s] ----
__global__ __launch_bounds__(256) void kvpart2_k(const unsigned short* __restrict__ KVt,
                                                 float* __restrict__ part) {
  const int bh = blockIdx.x, ch = blockIdx.y;
  const int b = bh >> 4, h = bh & 15;
  __shared__ unsigned short tl[32768];  // 4 bufs x (A[64][64] + B[64][64]) = 64 KiB
  const int tid = threadIdx.x;
  const int wave = tid >> 6, lane = tid & 63;
  const int lr = lane & 15, hi = lane >> 4;

  const int r0 = tid >> 3;
  const int cc0 = ((tid & 7) ^ (r0 & 7)) * 8;
  const int r1 = 32 + r0;
  const int cc1 = ((tid & 7) ^ (r1 & 7)) * 8;
  const unsigned short* A0 = KVt + ((size_t)(h * 64 + r0) * 4 + b) * 4096 + ch * 1024 + cc0;
  const unsigned short* A1 = KVt + ((size_t)(h * 64 + r1) * 4 + b) * 4096 + ch * 1024 + cc1;
  const unsigned short* B0 = KVt + ((size_t)(1024 + h * 64 + r0) * 4 + b) * 4096 + ch * 1024 + cc0;
  const unsigned short* B1 = KVt + ((size_t)(1024 + h * 64 + r1) * 4 + b) * 4096 + ch * 1024 + cc1;

#define KSTAGE(tt) { int bb2 = ((tt) & 3) * 8192; \
    load_lds16(A0 + (tt) * 64, &tl[bb2 + tid * 8]); \
    load_lds16(A1 + (tt) * 64, &tl[bb2 + 2048 + tid * 8]); \
    load_lds16(B0 + (tt) * 64, &tl[bb2 + 4096 + tid * 8]); \
    load_lds16(B1 + (tt) * 64, &tl[bb2 + 6144 + tid * 8]); }

  const int ra = wave * 16 + lr;
  const int aoff = ra * 64;
  const int ach0 = (hi ^ (ra & 7)) * 8, ach1 = ((4 + hi) ^ (ra & 7)) * 8;

  f32x4 acc4[4];
#pragma unroll
  for (int nt = 0; nt < 4; ++nt) acc4[nt] = (f32x4){0.f, 0.f, 0.f, 0.f};

  KSTAGE(0) KSTAGE(1)
  asm volatile("s_waitcnt vmcnt(4)" ::: "memory");
  __builtin_amdgcn_s_barrier();
  for (int t = 0; t < 16; ++t) {
    const int bb = (t & 3) * 8192;
    if (t + 2 < 16) KSTAGE(t + 2)
    bf16x8 a0 = *(const bf16x8*)&tl[bb + aoff + ach0];
    bf16x8 a1 = *(const bf16x8*)&tl[bb + aoff + ach1];
    bf16x8 bf0[4], bf1[4];
#pragma unroll
    for (int nt = 0; nt < 4; ++nt) {
      int rb = nt * 16 + lr;
      bf0[nt] = *(const bf16x8*)&tl[bb + 4096 + rb * 64 + ((hi ^ (rb & 7)) * 8)];
      bf1[nt] = *(const bf16x8*)&tl[bb + 4096 + rb * 64 + (((4 + hi) ^ (rb & 7)) * 8)];
    }
#pragma unroll
    for (int nt = 0; nt < 4; ++nt) {
      acc4[nt] = __builtin_amdgcn_mfma_f32_16x16x32_bf16(a0, bf0[nt], acc4[nt], 0, 0, 0);
      acc4[nt] = __builtin_amdgcn_mfma_f32_16x16x32_bf16(a1, bf1[nt], acc4[nt], 0, 0, 0);
    }
    if (t < 14) asm volatile("s_waitcnt vmcnt(4)" ::: "memory");
    else        asm volatile("s_waitcnt vmcnt(0)" ::: "memory");
    __builtin_amdgcn_s_barrier();
  }
  float* dst = part + ((size_t)ch * 64 + bh) * 4096;
#pragma unroll
  for (int nt = 0; nt < 4; ++nt)
#pragma unroll
    for (int j = 0; j < 4; ++j)
      dst[(wave * 16 + hi * 4 + j) * 64 + nt * 16 + lr] = acc4[nt][j];
#undef KSTAGE
}

// kv[bh*4096 + d*64 + e] = norm[b] * sum_ch part  (grid 1024 x 256)
__global__ void kvreduce_k(const float* __restrict__ part, const float* __restrict__ norm,
                           float* __restrict__ kv) {
  int idx = blockIdx.x * 256 + threadIdx.x;
  int b = idx >> 16;
  float s = 0.f;
#pragma unroll
  for (int ch = 0; ch < NCH; ++ch) s += part[(size_t)ch * 262144 + idx];
  kv[idx] = s * norm[b];
}

__global__ void bias2_k(const float* __restrict__ bq, const float* __restrict__ kv,
                        float* __restrict__ bias2) {
  int idx = blockIdx.x * 256 + threadIdx.x;
  int b = idx >> 10, n = idx & 1023, h = n >> 6, e = n & 63;
  const float* kvp = kv + ((size_t)(b * 16 + h)) * 4096 + e;
  float s = 0.f;
#pragma unroll
  for (int d = 0; d < 64; ++d) s += bq[h * 64 + d] * kvp[d * 64];
  bias2[idx] = s;
}

__global__ __launch_bounds__(128) void wprime_k(const float* __restrict__ Wq,
                                                const float* __restrict__ kv,
                                                unsigned short* __restrict__ Wpt) {
  int bh = blockIdx.y, b = bh >> 4, h = bh & 15;
  int c0 = blockIdx.x * 128;
  __shared__ float wqs[128][65];
  __shared__ float kvs[64][64];
  int tid = threadIdx.x;
  for (int i = 0; i < 32; ++i) {
    int idx = i * 128 + tid;
    ((float*)kvs)[idx] = kv[(size_t)bh * 4096 + idx];
  }
  int rr = tid >> 6, cc = tid & 63;
  for (int i = 0; i < 64; ++i) {
    int r = i * 2 + rr;
    wqs[r][cc] = Wq[(size_t)(c0 + r) * HIDDEN + h * 64 + cc];
  }
  __syncthreads();
  float acc[64];
#pragma unroll
  for (int e = 0; e < 64; ++e) acc[e] = 0.f;
  for (int d = 0; d < 64; ++d) {
    float w = wqs[tid][d];
#pragma unroll
    for (int e4 = 0; e4 < 64; e4 += 4) {
      f32x4 kvv = *(const f32x4*)&kvs[d][e4];
      acc[e4 + 0] += w * kvv[0];
      acc[e4 + 1] += w * kvv[1];
      acc[e4 + 2] += w * kvv[2];
      acc[e4 + 3] += w * kvv[3];
    }
  }
  unsigned short* dst = Wpt + (size_t)b * HIDDEN * HIDDEN + (size_t)(h * 64) * HIDDEN + (c0 + tid);
#pragma unroll
  for (int e = 0; e < 64; ++e) dst[(size_t)e * HIDDEN] = f2bf(acc[e]);
}

// ---------------- launch ----------------
extern "C" void kernel_launch(void* const* d_in, const int* in_sizes, int n_in,
                              void* d_out, int out_size, void* d_ws, size_t ws_size,
                              hipStream_t stream) {
  const float* x = (const float*)d_in[0];
  const float* mask = (const float*)d_in[1];
  const float* Wq = (const float*)d_in[2];
  const float* bq = (const float*)d_in[3];
  const float* Wk = (const float*)d_in[4];
  const float* bk = (const float*)d_in[5];
  const float* Wv = (const float*)d_in[6];
  const float* bv = (const float*)d_in[7];
  float* out = (float*)d_out;

  char* w = (char*)d_ws;
  unsigned short* xb = (unsigned short*)w;  w += (size_t)M_TOT * HIDDEN * 2;           // 32 MiB
  unsigned short* Bt = (unsigned short*)w;  w += (size_t)2048 * HIDDEN * 2;            // 4 MiB
  unsigned short* KVt = (unsigned short*)w; w += (size_t)2048 * BATCH * SEQ * 2;       // 64 MiB
  float* part = (float*)w;                  w += (size_t)NCH * 64 * 4096 * 4;          // 4 MiB
  float* kv = (float*)w;                    w += (size_t)64 * 4096 * 4;                // 1 MiB
  unsigned short* Wpt = (unsigned short*)w; w += (size_t)BATCH * HIDDEN * HIDDEN * 2;  // 8 MiB
  float* bkv = (float*)w;                   w += 2048 * 4;
  float* bias2 = (float*)w;                 w += 4096 * 4;
  float* norm = (float*)w;                  w += 64;

  prep_k<<<dim3(8716), dim3(256), 0, stream>>>(x, xb, Wk, Wv, Bt, bk, bv, bkv, mask, norm);
  // KV projection: M=16384, N=2048, K=1024 -> 512 blocks; writes transposed KVt
  gemm256_k<2, 0><<<dim3(512), dim3(512), 0, stream>>>(xb, Bt, bkv, mask, (void*)KVt, 0, 8);
  kvpart2_k<<<dim3(64, NCH), dim3(256), 0, stream>>>(KVt, part);
  kvreduce_k<<<dim3(1024), dim3(256), 0, stream>>>(part, norm, kv);
  bias2_k<<<dim3(16), dim3(256), 0, stream>>>(bq, kv, bias2);
  wprime_k<<<dim3(8, 64), dim3(128), 0, stream>>>(Wq, kv, Wpt);
  // out GEMM: M=16384, N=1024, K=1024 -> 256 blocks; f32 out
  gemm256_k<0, 1><<<dim3(256), dim3(512), 0, stream>>>(xb, Wpt, bias2, mask, (void*)out, 1024, 4);
}